// Round 4
// baseline (397.753 us; speedup 1.0000x reference)
//
#include <hip/hip_runtime.h>
#include <cstdint>
#include <cstddef>

#define NEG_SLOPE 0.2f
#define HC 512
#define NH 4

typedef __attribute__((ext_vector_type(8))) short bf16x8;
typedef __attribute__((ext_vector_type(4))) float f32x4;

__device__ inline float lrelu(float z) { return z > 0.f ? z : NEG_SLOPE * z; }

__device__ inline unsigned short f2bf(float f) {            // RNE
    unsigned u = __float_as_uint(f);
    u += 0x7FFFu + ((u >> 16) & 1u);
    return (unsigned short)(u >> 16);
}
__device__ inline float bflo(unsigned v) { return __uint_as_float(v << 16); }
__device__ inline float bfhi(unsigned v) { return __uint_as_float(v & 0xffff0000u); }

#define GLOAD16(gp, lp) \
    __builtin_amdgcn_global_load_lds( \
        (const __attribute__((address_space(1))) unsigned int*)(const void*)(gp), \
        (__attribute__((address_space(3))) unsigned int*)(void*)(lp), 16, 0, 0)

// ---------------------------------------------------------------------------
__global__ void detect_kernel(const int* __restrict__ ei, int E, int* __restrict__ flag) {
    __shared__ int nz;
    if (threadIdx.x == 0) nz = 0;
    __syncthreads();
    int lim = E < 256 ? E : 256;
    if (threadIdx.x < lim)
        if (ei[2 * threadIdx.x + 1] != 0) atomicOr(&nz, 1);
    __syncthreads();
    if (threadIdx.x == 0) *flag = (nz == 0) ? 1 : 0;        // 1 -> int64
}

__device__ inline int edge_read(const int* ei, int is64, size_t idx) {
    return is64 ? ei[2 * idx] : ei[idx];
}

// ---------------------------------------------------------------------------
__global__ __launch_bounds__(256) void cast_kernel(const float* __restrict__ src,
                                                   unsigned short* __restrict__ dst, int n4) {
    int i = blockIdx.x * 256 + threadIdx.x;
    if (i >= n4) return;
    float4 v = reinterpret_cast<const float4*>(src)[i];
    ushort4 o;
    o.x = f2bf(v.x); o.y = f2bf(v.y); o.z = f2bf(v.z); o.w = f2bf(v.w);
    reinterpret_cast<ushort4*>(dst)[i] = o;
}

__global__ __launch_bounds__(256) void castT_kernel(const float* __restrict__ src,
                                                    unsigned short* __restrict__ dstT,
                                                    int R, int C) {
    int idx = blockIdx.x * 256 + threadIdx.x;
    if (idx >= R * C) return;
    int r = idx / C;
    int c = idx - r * C;
    dstT[(size_t)c * R + r] = f2bf(src[idx]);
}

// ---------------------------------------------------------------------------
// Precompute: watt[0..3][256] = W_h @ att_src_h ; watt[4..7][256] = W_h @ att_dst_h
//             sh[h] = W_edge_h . att_edge_h ;  bc = bias @ W_out + b_out
__global__ __launch_bounds__(256) void prep_kernel(
        const float* __restrict__ W, const float* __restrict__ att_s,
        const float* __restrict__ att_d, const float* __restrict__ W_edge,
        const float* __restrict__ att_edge, const float* __restrict__ bias,
        const float* __restrict__ W_out, const float* __restrict__ b_out,
        float* __restrict__ watt, float* __restrict__ sh, float* __restrict__ bc) {
    int t = threadIdx.x;            // 256 threads; t = emb dim k / out col
    #pragma unroll
    for (int h = 0; h < NH; ++h) {
        float ss = 0.f, dd = 0.f;
        for (int c = 0; c < 128; ++c) {
            float w = W[(size_t)t * HC + h * 128 + c];
            ss += w * att_s[h * 128 + c];
            dd += w * att_d[h * 128 + c];
        }
        watt[h * 256 + t] = ss;
        watt[1024 + h * 256 + t] = dd;
    }
    if (t < NH) {
        float s = 0.f;
        for (int c = 0; c < 128; ++c) s += W_edge[t * 128 + c] * att_edge[t * 128 + c];
        sh[t] = s;
    }
    float b = 0.f;
    for (int j = 0; j < HC; ++j) b += bias[j] * W_out[(size_t)j * 256 + t];
    bc[t] = b + b_out[t];
}

// ---------------------------------------------------------------------------
// a_src[n,h] = emb[n] . watt_s[h] ; a_dst likewise. One wave per node.
__global__ __launch_bounds__(256) void attdot_kernel(
        const uint2* __restrict__ embq, const float* __restrict__ watt,
        float* __restrict__ a_src, float* __restrict__ a_dst, int N) {
    __shared__ float sw[8][256];
    int t = threadIdx.x;
    #pragma unroll
    for (int i = 0; i < 8; ++i) sw[i][t] = watt[i * 256 + t];
    __syncthreads();
    int wid = t >> 6, lane = t & 63;
    int n = blockIdx.x * 4 + wid;
    if (n >= N) return;
    uint2 v = embq[(size_t)n * 64 + lane];
    float d0 = bflo(v.x), d1 = bfhi(v.x), d2 = bflo(v.y), d3 = bfhi(v.y);
    float r[8];
    #pragma unroll
    for (int i = 0; i < 8; ++i) {
        const float* wv = &sw[i][lane * 4];
        r[i] = d0 * wv[0] + d1 * wv[1] + d2 * wv[2] + d3 * wv[3];
    }
    #pragma unroll
    for (int o = 32; o > 0; o >>= 1) {
        #pragma unroll
        for (int i = 0; i < 8; ++i) r[i] += __shfl_xor(r[i], o);
    }
    if (lane == 0) {
        size_t b = (size_t)n * 4;
        a_src[b + 0] = r[0]; a_src[b + 1] = r[1];
        a_src[b + 2] = r[2]; a_src[b + 3] = r[3];
        a_dst[b + 0] = r[4]; a_dst[b + 1] = r[5];
        a_dst[b + 2] = r[6]; a_dst[b + 3] = r[7];
    }
}

// ---------------------------------------------------------------------------
__global__ __launch_bounds__(256) void edge_stats_kernel(
        const int* __restrict__ ei, const float* __restrict__ ew,
        const int* __restrict__ flag, int* __restrict__ cnt,
        float* __restrict__ wsum, int E) {
    int e = blockIdx.x * 256 + threadIdx.x;
    if (e >= E) return;
    int is64 = *flag;
    int d = edge_read(ei, is64, (size_t)E + e);
    atomicAdd(&cnt[d], 1);
    atomicAdd(&wsum[d], ew[e]);
}

// ---------------------------------------------------------------------------
__global__ __launch_bounds__(256) void scan1_kernel(
        const int* __restrict__ cnt, const float* __restrict__ wsum,
        int* __restrict__ offsets, int* __restrict__ bsum,
        float* __restrict__ ea_mean, int N) {
    int b = blockIdx.x, t = threadIdx.x, i = b * 256 + t;
    int v = (i < N) ? cnt[i] : 0;
    if (i < N) ea_mean[i] = wsum[i] / fmaxf((float)v, 1.f);
    int lane = t & 63, w = t >> 6;
    int s = v;
    #pragma unroll
    for (int o = 1; o < 64; o <<= 1) {
        int u = __shfl_up(s, o);
        if (lane >= o) s += u;
    }
    __shared__ int ws_[4];
    if (lane == 63) ws_[w] = s;
    __syncthreads();
    int base = 0;
    for (int k = 0; k < 4; ++k) if (k < w) base += ws_[k];
    if (i < N) offsets[i] = base + s - v;
    if (t == 0) bsum[b] = ws_[0] + ws_[1] + ws_[2] + ws_[3];
}

__global__ __launch_bounds__(256) void scan2_kernel(
        const int* __restrict__ bsum, int* __restrict__ bbase, int nb,
        int* __restrict__ offsets, int N, int E) {
    int t = threadIdx.x;
    int v = (t < nb) ? bsum[t] : 0;
    int lane = t & 63, w = t >> 6;
    int s = v;
    #pragma unroll
    for (int o = 1; o < 64; o <<= 1) {
        int u = __shfl_up(s, o);
        if (lane >= o) s += u;
    }
    __shared__ int ws_[4];
    if (lane == 63) ws_[w] = s;
    __syncthreads();
    int base = 0;
    for (int k = 0; k < 4; ++k) if (k < w) base += ws_[k];
    if (t < nb) bbase[t] = base + s - v;
    if (t == 0) offsets[N] = E;
}

__global__ __launch_bounds__(256) void scan3_kernel(
        int* __restrict__ offsets, const int* __restrict__ bbase, int N) {
    int i = blockIdx.x * 256 + threadIdx.x;
    if (i < N) offsets[i] += bbase[blockIdx.x];
}

// ---------------------------------------------------------------------------
__global__ __launch_bounds__(256) void fill_kernel(
        const int* __restrict__ ei, const int* __restrict__ flag,
        const int* __restrict__ offsets, int* __restrict__ fill,
        int* __restrict__ csr, int E) {
    int e = blockIdx.x * 256 + threadIdx.x;
    if (e >= E) return;
    int is64 = *flag;
    int d = edge_read(ei, is64, (size_t)E + e);
    int pos = offsets[d] + atomicAdd(&fill[d], 1);
    csr[pos] = e;
}

// ---------------------------------------------------------------------------
// One WAVE per dst node, aggregating in EMB space (256 dims, 512 B rows).
// Lane owns 4 dims (uint2 per row). Per edge: 1 x 8B gather feeds all 4 heads.
// Epilogue: per-head normalize, write aggn[n][h][256] bf16.
__global__ __launch_bounds__(256) void agg_kernel(
        const uint2* __restrict__ embq, const float* __restrict__ a_src,
        const float* __restrict__ a_dst, const float* __restrict__ ea_mean,
        const float* __restrict__ sh, const float* __restrict__ ew,
        const int* __restrict__ ei, const int* __restrict__ flag,
        const int* __restrict__ csr, const int* __restrict__ offsets,
        uint2* __restrict__ aggn, int N) {
    int wid = threadIdx.x >> 6, lane = threadIdx.x & 63;
    int n = blockIdx.x * 4 + wid;
    if (n >= N) return;
    int is64 = *flag;
    int beg = offsets[n], end = offsets[n + 1];

    __shared__ int s_src[4][64];
    __shared__ __align__(16) float s_alpha[4][64][4];

    float ad0 = a_dst[(size_t)n * 4 + 0], ad1 = a_dst[(size_t)n * 4 + 1];
    float ad2 = a_dst[(size_t)n * 4 + 2], ad3 = a_dst[(size_t)n * 4 + 3];
    float sh0 = sh[0], sh1 = sh[1], sh2 = sh[2], sh3 = sh[3];
    float eam = ea_mean[n];
    float es0 = __expf(lrelu(a_src[(size_t)n * 4 + 0] + ad0 + eam * sh0));
    float es1 = __expf(lrelu(a_src[(size_t)n * 4 + 1] + ad1 + eam * sh1));
    float es2 = __expf(lrelu(a_src[(size_t)n * 4 + 2] + ad2 + eam * sh2));
    float es3 = __expf(lrelu(a_src[(size_t)n * 4 + 3] + ad3 + eam * sh3));

    uint2 xv = embq[(size_t)n * 64 + lane];     // self loop row
    float d0 = bflo(xv.x), d1 = bfhi(xv.x), d2 = bflo(xv.y), d3 = bfhi(xv.y);

    float a00 = es0 * d0, a01 = es0 * d1, a02 = es0 * d2, a03 = es0 * d3;
    float a10 = es1 * d0, a11 = es1 * d1, a12 = es1 * d2, a13 = es1 * d3;
    float a20 = es2 * d0, a21 = es2 * d1, a22 = es2 * d2, a23 = es2 * d3;
    float a30 = es3 * d0, a31 = es3 * d1, a32 = es3 * d2, a33 = es3 * d3;
    float den0 = es0, den1 = es1, den2 = es2, den3 = es3;

    for (int cb = beg; cb < end; cb += 64) {
        int m = end - cb; if (m > 64) m = 64;
        if (lane < m) {
            int e = csr[cb + lane];
            int s = edge_read(ei, is64, (size_t)e);
            float wgt = ew[e];
            s_src[wid][lane] = s;
            float4 as4 = *reinterpret_cast<const float4*>(&a_src[(size_t)s * 4]);
            s_alpha[wid][lane][0] = __expf(lrelu(as4.x + ad0 + wgt * sh0));
            s_alpha[wid][lane][1] = __expf(lrelu(as4.y + ad1 + wgt * sh1));
            s_alpha[wid][lane][2] = __expf(lrelu(as4.z + ad2 + wgt * sh2));
            s_alpha[wid][lane][3] = __expf(lrelu(as4.w + ad3 + wgt * sh3));
        }
        // per-wave LDS slice + same-wave ordering: no barrier needed
        int e2 = 0;
        for (; e2 + 2 <= m; e2 += 2) {
            int s0 = s_src[wid][e2], s1 = s_src[wid][e2 + 1];
            float4 w0 = *reinterpret_cast<const float4*>(s_alpha[wid][e2]);
            float4 w1 = *reinterpret_cast<const float4*>(s_alpha[wid][e2 + 1]);
            uint2 v0 = embq[(size_t)s0 * 64 + lane];
            uint2 v1 = embq[(size_t)s1 * 64 + lane];
            float e00 = bflo(v0.x), e01 = bfhi(v0.x), e02 = bflo(v0.y), e03 = bfhi(v0.y);
            float e10 = bflo(v1.x), e11 = bfhi(v1.x), e12 = bflo(v1.y), e13 = bfhi(v1.y);
            a00 += w0.x * e00 + w1.x * e10;  a01 += w0.x * e01 + w1.x * e11;
            a02 += w0.x * e02 + w1.x * e12;  a03 += w0.x * e03 + w1.x * e13;
            a10 += w0.y * e00 + w1.y * e10;  a11 += w0.y * e01 + w1.y * e11;
            a12 += w0.y * e02 + w1.y * e12;  a13 += w0.y * e03 + w1.y * e13;
            a20 += w0.z * e00 + w1.z * e10;  a21 += w0.z * e01 + w1.z * e11;
            a22 += w0.z * e02 + w1.z * e12;  a23 += w0.z * e03 + w1.z * e13;
            a30 += w0.w * e00 + w1.w * e10;  a31 += w0.w * e01 + w1.w * e11;
            a32 += w0.w * e02 + w1.w * e12;  a33 += w0.w * e03 + w1.w * e13;
            den0 += w0.x + w1.x; den1 += w0.y + w1.y;
            den2 += w0.z + w1.z; den3 += w0.w + w1.w;
        }
        if (e2 < m) {
            int s0 = s_src[wid][e2];
            float4 w0 = *reinterpret_cast<const float4*>(s_alpha[wid][e2]);
            uint2 v0 = embq[(size_t)s0 * 64 + lane];
            float e00 = bflo(v0.x), e01 = bfhi(v0.x), e02 = bflo(v0.y), e03 = bfhi(v0.y);
            a00 += w0.x * e00; a01 += w0.x * e01; a02 += w0.x * e02; a03 += w0.x * e03;
            a10 += w0.y * e00; a11 += w0.y * e01; a12 += w0.y * e02; a13 += w0.y * e03;
            a20 += w0.z * e00; a21 += w0.z * e01; a22 += w0.z * e02; a23 += w0.z * e03;
            a30 += w0.w * e00; a31 += w0.w * e01; a32 += w0.w * e02; a33 += w0.w * e03;
            den0 += w0.x; den1 += w0.y; den2 += w0.z; den3 += w0.w;
        }
    }

    float i0 = 1.f / (den0 + 1e-16f), i1 = 1.f / (den1 + 1e-16f);
    float i2 = 1.f / (den2 + 1e-16f), i3 = 1.f / (den3 + 1e-16f);
    size_t base = (size_t)n * 256 + lane;       // uint2 units; head stride 64
    uint2 o;
    o.x = (unsigned)f2bf(a00 * i0) | ((unsigned)f2bf(a01 * i0) << 16);
    o.y = (unsigned)f2bf(a02 * i0) | ((unsigned)f2bf(a03 * i0) << 16);
    aggn[base] = o;
    o.x = (unsigned)f2bf(a10 * i1) | ((unsigned)f2bf(a11 * i1) << 16);
    o.y = (unsigned)f2bf(a12 * i1) | ((unsigned)f2bf(a13 * i1) << 16);
    aggn[base + 64] = o;
    o.x = (unsigned)f2bf(a20 * i2) | ((unsigned)f2bf(a21 * i2) << 16);
    o.y = (unsigned)f2bf(a22 * i2) | ((unsigned)f2bf(a23 * i2) << 16);
    aggn[base + 128] = o;
    o.x = (unsigned)f2bf(a30 * i3) | ((unsigned)f2bf(a31 * i3) << 16);
    o.y = (unsigned)f2bf(a32 * i3) | ((unsigned)f2bf(a33 * i3) << 16);
    aggn[base + 192] = o;
}

// ---------------------------------------------------------------------------
// bf16 MFMA GEMM with strides + z-batching:
//   C[row, zC + col] = A[zA + row*lda : +K] . BT[zB + (col)*ldb : +K]
// 128x128 tile, BK=64, 4 waves, 16x16x32 MFMA, both-sides XOR swizzle.
template<int K, bool BIAS, bool OUT_BF16>
__global__ __launch_bounds__(256) void gemm_bf16(
        const unsigned short* __restrict__ A, int lda, size_t aStrideZ,
        const unsigned short* __restrict__ BT, int ldb, size_t bStrideZ,
        const float* __restrict__ bias,
        unsigned short* __restrict__ Cb, float* __restrict__ Cf,
        int ldc, size_t cStrideZ, int M) {
    __shared__ __align__(16) unsigned short As[128 * 64];
    __shared__ __align__(16) unsigned short Bs[128 * 64];
    int tid = threadIdx.x;
    int lane = tid & 63, w = tid >> 6;
    int bm = blockIdx.y * 128, bn = blockIdx.x * 128;
    int z = blockIdx.z;
    A  += (size_t)z * aStrideZ;
    BT += (size_t)z * bStrideZ;
    size_t cOff = (size_t)z * cStrideZ;
    int wr = w >> 1, wc = w & 1;

    f32x4 acc[4][4];
    #pragma unroll
    for (int i = 0; i < 4; ++i)
        #pragma unroll
        for (int j = 0; j < 4; ++j)
            acc[i][j] = (f32x4){0.f, 0.f, 0.f, 0.f};

    int lr = lane & 15, kb = lane >> 4;
    int q = lane & 7;

    for (int k0 = 0; k0 < K; k0 += 64) {
        #pragma unroll
        for (int p = 0; p < 4; ++p) {
            int row = p * 32 + w * 8 + (lane >> 3);
            int ce  = ((q ^ (row & 7)) << 3) + k0;
            int ob  = p * 4096 + w * 1024;
            int gr = bm + row; if (gr >= M) gr = M - 1;
            GLOAD16(A + (size_t)gr * lda + ce, (char*)As + ob);
            int gn = bn + row;
            GLOAD16(BT + (size_t)gn * ldb + ce, (char*)Bs + ob);
        }
        __syncthreads();

        #pragma unroll
        for (int kk = 0; kk < 2; ++kk) {
            bf16x8 a[4], b[4];
            #pragma unroll
            for (int i = 0; i < 4; ++i) {
                int row = wr * 64 + i * 16 + lr;
                a[i] = *reinterpret_cast<const bf16x8*>(
                    &As[row * 64 + (((kk * 4 + kb) ^ (row & 7)) << 3)]);
            }
            #pragma unroll
            for (int j = 0; j < 4; ++j) {
                int row = wc * 64 + j * 16 + lr;
                b[j] = *reinterpret_cast<const bf16x8*>(
                    &Bs[row * 64 + (((kk * 4 + kb) ^ (row & 7)) << 3)]);
            }
            #pragma unroll
            for (int i = 0; i < 4; ++i)
                #pragma unroll
                for (int j = 0; j < 4; ++j)
                    acc[i][j] = __builtin_amdgcn_mfma_f32_16x16x32_bf16(a[i], b[j], acc[i][j], 0, 0, 0);
        }
        __syncthreads();
    }

    int rg = lane >> 4;
    #pragma unroll
    for (int i = 0; i < 4; ++i) {
        #pragma unroll
        for (int r = 0; r < 4; ++r) {
            int row = bm + wr * 64 + i * 16 + rg * 4 + r;
            if (row >= M) continue;
            #pragma unroll
            for (int j = 0; j < 4; ++j) {
                int col = bn + wc * 64 + j * 16 + lr;
                float v = acc[i][j][r];
                if (BIAS) v += bias[col];
                if (OUT_BF16) Cb[(size_t)row * ldc + cOff + col] = f2bf(v);
                else          Cf[(size_t)row * ldc + cOff + col] = v;
            }
        }
    }
}

// ---------------------------------------------------------------------------
extern "C" void kernel_launch(void* const* d_in, const int* in_sizes, int n_in,
                              void* d_out, int out_size, void* d_ws, size_t ws_size,
                              hipStream_t stream) {
    const int*   edge_index  = (const int*)d_in[0];
    const float* edge_weight = (const float*)d_in[1];
    const float* emb         = (const float*)d_in[2];
    const float* W           = (const float*)d_in[3];
    const float* att_src     = (const float*)d_in[4];
    const float* att_dst     = (const float*)d_in[5];
    const float* att_edge    = (const float*)d_in[6];
    const float* W_edge      = (const float*)d_in[7];
    const float* bias        = (const float*)d_in[8];
    const float* W_out       = (const float*)d_in[9];
    const float* b_out       = (const float*)d_in[10];
    float* out = (float*)d_out;

    const int E = in_sizes[1];
    const int D = 256;
    const int N = in_sizes[2] / D;
    const int nb = (N + 255) / 256;
    const int mb = (N + 127) / 128;

    char* ws = (char*)d_ws;
    size_t off = 0;
    auto alloc = [&](size_t bytes) {
        size_t o = off;
        off += (bytes + 255) & ~(size_t)255;
        return o;
    };
    unsigned short* embb  = (unsigned short*)(ws + alloc((size_t)N * D * 2));       // [N][256] bf16
    unsigned short* aggn  = (unsigned short*)(ws + alloc((size_t)N * 1024 * 2));    // [N][4][256] bf16
    unsigned short* tmp   = (unsigned short*)(ws + alloc((size_t)N * HC * 2));      // [N][512] bf16
    unsigned short* WT    = (unsigned short*)(ws + alloc((size_t)D * HC * 2));      // [512][256] = W^T
    unsigned short* WoT   = (unsigned short*)(ws + alloc((size_t)HC * D * 2));      // [256][512] = W_out^T
    float* watt    = (float*)(ws + alloc(2048 * 4));       // [8][256]
    float* bc      = (float*)(ws + alloc(256 * 4));
    float* a_src   = (float*)(ws + alloc((size_t)N * 4 * 4));
    float* a_dst   = (float*)(ws + alloc((size_t)N * 4 * 4));
    float* sh      = (float*)(ws + alloc(64));
    float* ea_mean = (float*)(ws + alloc((size_t)N * 4));
    size_t zoff    = alloc((size_t)N * 4 * 3);             // wsum | cnt | fill
    float* wsum    = (float*)(ws + zoff);
    int*   cnt     = (int*)(ws + zoff + (size_t)N * 4);
    int*   fillc   = (int*)(ws + zoff + (size_t)N * 8);
    int*   offsets = (int*)(ws + alloc((size_t)(N + 1) * 4));
    int*   csr     = (int*)(ws + alloc((size_t)E * 4));
    int*   bsum    = (int*)(ws + alloc((size_t)nb * 4));
    int*   bbase   = (int*)(ws + alloc((size_t)nb * 4));
    int*   flag    = (int*)(ws + alloc(4));
    (void)ws_size; (void)n_in; (void)out_size;

    hipMemsetAsync(ws + zoff, 0, (size_t)N * 4 * 3, stream);
    detect_kernel<<<1, 256, 0, stream>>>(edge_index, E, flag);

    cast_kernel<<<((N * D / 4) + 255) / 256, 256, 0, stream>>>(emb, embb, N * D / 4);
    castT_kernel<<<(D * HC + 255) / 256, 256, 0, stream>>>(W, WT, D, HC);
    castT_kernel<<<(HC * D + 255) / 256, 256, 0, stream>>>(W_out, WoT, HC, D);
    prep_kernel<<<1, 256, 0, stream>>>(W, att_src, att_dst, W_edge, att_edge,
                                       bias, W_out, b_out, watt, sh, bc);

    attdot_kernel<<<(N + 3) / 4, 256, 0, stream>>>((const uint2*)embb, watt,
                                                   a_src, a_dst, N);

    edge_stats_kernel<<<(E + 255) / 256, 256, 0, stream>>>(
        edge_index, edge_weight, flag, cnt, wsum, E);
    scan1_kernel<<<nb, 256, 0, stream>>>(cnt, wsum, offsets, bsum, ea_mean, N);
    scan2_kernel<<<1, 256, 0, stream>>>(bsum, bbase, nb, offsets, N, E);
    scan3_kernel<<<nb, 256, 0, stream>>>(offsets, bbase, N);
    fill_kernel<<<(E + 255) / 256, 256, 0, stream>>>(
        edge_index, flag, offsets, fillc, csr, E);

    agg_kernel<<<(N + 3) / 4, 256, 0, stream>>>(
        (const uint2*)embb, a_src, a_dst, ea_mean, sh, edge_weight, edge_index,
        flag, csr, offsets, (uint2*)aggn, N);

    // tmp[:, h*128:(h+1)*128] = aggn_h @ W_h      (z = head)
    gemm_bf16<256, false, true><<<dim3(1, mb, 4), 256, 0, stream>>>(
        aggn, 1024, (size_t)256,      // A: row stride 1024, head offset 256
        WT, 256, (size_t)128 * 256,   // B: W_h^T = rows h*128.. of WT
        nullptr, tmp, nullptr, 512, (size_t)128, N);

    // out = tmp @ W_out + bc
    gemm_bf16<512, true, false><<<dim3(2, mb, 1), 256, 0, stream>>>(
        tmp, 512, (size_t)0,
        WoT, 512, (size_t)0,
        bc, nullptr, out, 256, (size_t)0, N);
}

// Round 5
// 383.822 us; speedup vs baseline: 1.0363x; 1.0363x over previous
//
#include <hip/hip_runtime.h>
#include <cstdint>
#include <cstddef>

#define NEG_SLOPE 0.2f
#define HC 512
#define NH 4

typedef __attribute__((ext_vector_type(8))) short bf16x8;
typedef __attribute__((ext_vector_type(4))) float f32x4;

__device__ inline float lrelu(float z) { return z > 0.f ? z : NEG_SLOPE * z; }

__device__ inline unsigned short f2bf(float f) {            // RNE
    unsigned u = __float_as_uint(f);
    u += 0x7FFFu + ((u >> 16) & 1u);
    return (unsigned short)(u >> 16);
}
__device__ inline float bflo(unsigned v) { return __uint_as_float(v << 16); }
__device__ inline float bfhi(unsigned v) { return __uint_as_float(v & 0xffff0000u); }

#define GLOAD16(gp, lp) \
    __builtin_amdgcn_global_load_lds( \
        (const __attribute__((address_space(1))) unsigned int*)(const void*)(gp), \
        (__attribute__((address_space(3))) unsigned int*)(void*)(lp), 16, 0, 0)

// ---------------------------------------------------------------------------
__global__ void detect_kernel(const int* __restrict__ ei, int E, int* __restrict__ flag) {
    __shared__ int nz;
    if (threadIdx.x == 0) nz = 0;
    __syncthreads();
    int lim = E < 256 ? E : 256;
    if (threadIdx.x < lim)
        if (ei[2 * threadIdx.x + 1] != 0) atomicOr(&nz, 1);
    __syncthreads();
    if (threadIdx.x == 0) *flag = (nz == 0) ? 1 : 0;        // 1 -> int64
}

__device__ inline int edge_read(const int* ei, int is64, size_t idx) {
    return is64 ? ei[2 * idx] : ei[idx];
}

// ---------------------------------------------------------------------------
__global__ __launch_bounds__(256) void cast_kernel(const float* __restrict__ src,
                                                   unsigned short* __restrict__ dst, int n4) {
    int i = blockIdx.x * 256 + threadIdx.x;
    if (i >= n4) return;
    float4 v = reinterpret_cast<const float4*>(src)[i];
    ushort4 o;
    o.x = f2bf(v.x); o.y = f2bf(v.y); o.z = f2bf(v.z); o.w = f2bf(v.w);
    reinterpret_cast<ushort4*>(dst)[i] = o;
}

__global__ __launch_bounds__(256) void castT_kernel(const float* __restrict__ src,
                                                    unsigned short* __restrict__ dstT,
                                                    int R, int C) {
    int idx = blockIdx.x * 256 + threadIdx.x;
    if (idx >= R * C) return;
    int r = idx / C;
    int c = idx - r * C;
    dstT[(size_t)c * R + r] = f2bf(src[idx]);
}

// ---------------------------------------------------------------------------
// watt[0..3][256] = W_h @ att_src_h ; watt[4..7][256] = W_h @ att_dst_h
// sh[h] = W_edge_h . att_edge_h ;  bc = bias @ W_out + b_out
__global__ __launch_bounds__(256) void prep_kernel(
        const float* __restrict__ W, const float* __restrict__ att_s,
        const float* __restrict__ att_d, const float* __restrict__ W_edge,
        const float* __restrict__ att_edge, const float* __restrict__ bias,
        const float* __restrict__ W_out, const float* __restrict__ b_out,
        float* __restrict__ watt, float* __restrict__ sh, float* __restrict__ bc) {
    int t = threadIdx.x;
    #pragma unroll
    for (int h = 0; h < NH; ++h) {
        float ss = 0.f, dd = 0.f;
        for (int c = 0; c < 128; ++c) {
            float w = W[(size_t)t * HC + h * 128 + c];
            ss += w * att_s[h * 128 + c];
            dd += w * att_d[h * 128 + c];
        }
        watt[h * 256 + t] = ss;
        watt[1024 + h * 256 + t] = dd;
    }
    if (t < NH) {
        float s = 0.f;
        for (int c = 0; c < 128; ++c) s += W_edge[t * 128 + c] * att_edge[t * 128 + c];
        sh[t] = s;
    }
    float b = 0.f;
    for (int j = 0; j < HC; ++j) b += bias[j] * W_out[(size_t)j * 256 + t];
    bc[t] = b + b_out[t];
}

// ---------------------------------------------------------------------------
// Fused: bf16-cast emb + a_src/a_dst dots. One wave per node.
__global__ __launch_bounds__(256) void embcast_attdot_kernel(
        const float4* __restrict__ embf4, const float* __restrict__ watt,
        uint2* __restrict__ embq, float* __restrict__ a_src,
        float* __restrict__ a_dst, int N) {
    __shared__ float sw[8][256];
    int t = threadIdx.x;
    #pragma unroll
    for (int i = 0; i < 8; ++i) sw[i][t] = watt[i * 256 + t];
    __syncthreads();
    int wid = t >> 6, lane = t & 63;
    int n = blockIdx.x * 4 + wid;
    if (n >= N) return;
    float4 v = embf4[(size_t)n * 64 + lane];
    uint2 o;
    o.x = (unsigned)f2bf(v.x) | ((unsigned)f2bf(v.y) << 16);
    o.y = (unsigned)f2bf(v.z) | ((unsigned)f2bf(v.w) << 16);
    embq[(size_t)n * 64 + lane] = o;
    float r[8];
    #pragma unroll
    for (int i = 0; i < 8; ++i) {
        const float* wv = &sw[i][lane * 4];
        r[i] = v.x * wv[0] + v.y * wv[1] + v.z * wv[2] + v.w * wv[3];
    }
    #pragma unroll
    for (int off = 32; off > 0; off >>= 1) {
        #pragma unroll
        for (int i = 0; i < 8; ++i) r[i] += __shfl_xor(r[i], off);
    }
    if (lane == 0) {
        size_t b = (size_t)n * 4;
        a_src[b + 0] = r[0]; a_src[b + 1] = r[1];
        a_src[b + 2] = r[2]; a_src[b + 3] = r[3];
        a_dst[b + 0] = r[4]; a_dst[b + 1] = r[5];
        a_dst[b + 2] = r[6]; a_dst[b + 3] = r[7];
    }
}

// ---------------------------------------------------------------------------
__global__ __launch_bounds__(256) void edge_stats_kernel(
        const int* __restrict__ ei, const float* __restrict__ ew,
        const int* __restrict__ flag, int* __restrict__ cnt,
        float* __restrict__ wsum, int E) {
    int e = blockIdx.x * 256 + threadIdx.x;
    if (e >= E) return;
    int is64 = *flag;
    int d = edge_read(ei, is64, (size_t)E + e);
    atomicAdd(&cnt[d], 1);
    atomicAdd(&wsum[d], ew[e]);
}

// ---------------------------------------------------------------------------
__global__ __launch_bounds__(256) void scan1_kernel(
        const int* __restrict__ cnt, const float* __restrict__ wsum,
        int* __restrict__ offsets, int* __restrict__ bsum,
        float* __restrict__ ea_mean, int N) {
    int b = blockIdx.x, t = threadIdx.x, i = b * 256 + t;
    int v = (i < N) ? cnt[i] : 0;
    if (i < N) ea_mean[i] = wsum[i] / fmaxf((float)v, 1.f);
    int lane = t & 63, w = t >> 6;
    int s = v;
    #pragma unroll
    for (int o = 1; o < 64; o <<= 1) {
        int u = __shfl_up(s, o);
        if (lane >= o) s += u;
    }
    __shared__ int ws_[4];
    if (lane == 63) ws_[w] = s;
    __syncthreads();
    int base = 0;
    for (int k = 0; k < 4; ++k) if (k < w) base += ws_[k];
    if (i < N) offsets[i] = base + s - v;
    if (t == 0) bsum[b] = ws_[0] + ws_[1] + ws_[2] + ws_[3];
}

__global__ __launch_bounds__(256) void scan2_kernel(
        const int* __restrict__ bsum, int* __restrict__ bbase, int nb,
        int* __restrict__ offsets, int N, int E) {
    int t = threadIdx.x;
    int v = (t < nb) ? bsum[t] : 0;
    int lane = t & 63, w = t >> 6;
    int s = v;
    #pragma unroll
    for (int o = 1; o < 64; o <<= 1) {
        int u = __shfl_up(s, o);
        if (lane >= o) s += u;
    }
    __shared__ int ws_[4];
    if (lane == 63) ws_[w] = s;
    __syncthreads();
    int base = 0;
    for (int k = 0; k < 4; ++k) if (k < w) base += ws_[k];
    if (t < nb) bbase[t] = base + s - v;
    if (t == 0) offsets[N] = E;
}

__global__ __launch_bounds__(256) void scan3_kernel(
        int* __restrict__ offsets, const int* __restrict__ bbase, int N) {
    int i = blockIdx.x * 256 + threadIdx.x;
    if (i < N) offsets[i] += bbase[blockIdx.x];
}

// ---------------------------------------------------------------------------
__global__ __launch_bounds__(256) void fill_kernel(
        const int* __restrict__ ei, const int* __restrict__ flag,
        const int* __restrict__ offsets, int* __restrict__ fill,
        int* __restrict__ csr, int E) {
    int e = blockIdx.x * 256 + threadIdx.x;
    if (e >= E) return;
    int is64 = *flag;
    int d = edge_read(ei, is64, (size_t)E + e);
    int pos = offsets[d] + atomicAdd(&fill[d], 1);
    csr[pos] = e;
}

// ---------------------------------------------------------------------------
#define EFMA(W_, V_) { \
    float e0_ = bflo(V_.x), e1_ = bfhi(V_.x), e2_ = bflo(V_.y), e3_ = bfhi(V_.y); \
    a00 += W_.x * e0_; a01 += W_.x * e1_; a02 += W_.x * e2_; a03 += W_.x * e3_; \
    a10 += W_.y * e0_; a11 += W_.y * e1_; a12 += W_.y * e2_; a13 += W_.y * e3_; \
    a20 += W_.z * e0_; a21 += W_.z * e1_; a22 += W_.z * e2_; a23 += W_.z * e3_; \
    a30 += W_.w * e0_; a31 += W_.w * e1_; a32 += W_.w * e2_; a33 += W_.w * e3_; \
    den0 += W_.x; den1 += W_.y; den2 += W_.z; den3 += W_.w; }

// One WAVE per dst node, aggregating in EMB space. Lane owns 4 dims (uint2).
// Unroll-4 gather (4 independent 8B loads in flight per lane).
__global__ __launch_bounds__(256) void agg_kernel(
        const uint2* __restrict__ embq, const float* __restrict__ a_src,
        const float* __restrict__ a_dst, const float* __restrict__ ea_mean,
        const float* __restrict__ sh, const float* __restrict__ ew,
        const int* __restrict__ ei, const int* __restrict__ flag,
        const int* __restrict__ csr, const int* __restrict__ offsets,
        uint2* __restrict__ aggn, int N) {
    int wid = threadIdx.x >> 6, lane = threadIdx.x & 63;
    int n = blockIdx.x * 4 + wid;
    if (n >= N) return;
    int is64 = *flag;
    int beg = offsets[n], end = offsets[n + 1];

    __shared__ int s_src[4][64];
    __shared__ __align__(16) float s_alpha[4][64][4];

    float ad0 = a_dst[(size_t)n * 4 + 0], ad1 = a_dst[(size_t)n * 4 + 1];
    float ad2 = a_dst[(size_t)n * 4 + 2], ad3 = a_dst[(size_t)n * 4 + 3];
    float sh0 = sh[0], sh1 = sh[1], sh2 = sh[2], sh3 = sh[3];
    float eam = ea_mean[n];
    float es0 = __expf(lrelu(a_src[(size_t)n * 4 + 0] + ad0 + eam * sh0));
    float es1 = __expf(lrelu(a_src[(size_t)n * 4 + 1] + ad1 + eam * sh1));
    float es2 = __expf(lrelu(a_src[(size_t)n * 4 + 2] + ad2 + eam * sh2));
    float es3 = __expf(lrelu(a_src[(size_t)n * 4 + 3] + ad3 + eam * sh3));

    uint2 xv = embq[(size_t)n * 64 + lane];     // self loop row
    float d0 = bflo(xv.x), d1 = bfhi(xv.x), d2 = bflo(xv.y), d3 = bfhi(xv.y);

    float a00 = es0 * d0, a01 = es0 * d1, a02 = es0 * d2, a03 = es0 * d3;
    float a10 = es1 * d0, a11 = es1 * d1, a12 = es1 * d2, a13 = es1 * d3;
    float a20 = es2 * d0, a21 = es2 * d1, a22 = es2 * d2, a23 = es2 * d3;
    float a30 = es3 * d0, a31 = es3 * d1, a32 = es3 * d2, a33 = es3 * d3;
    float den0 = es0, den1 = es1, den2 = es2, den3 = es3;

    for (int cb = beg; cb < end; cb += 64) {
        int m = end - cb; if (m > 64) m = 64;
        if (lane < m) {
            int e = csr[cb + lane];
            int s = edge_read(ei, is64, (size_t)e);
            float wgt = ew[e];
            s_src[wid][lane] = s;
            float4 as4 = *reinterpret_cast<const float4*>(&a_src[(size_t)s * 4]);
            s_alpha[wid][lane][0] = __expf(lrelu(as4.x + ad0 + wgt * sh0));
            s_alpha[wid][lane][1] = __expf(lrelu(as4.y + ad1 + wgt * sh1));
            s_alpha[wid][lane][2] = __expf(lrelu(as4.z + ad2 + wgt * sh2));
            s_alpha[wid][lane][3] = __expf(lrelu(as4.w + ad3 + wgt * sh3));
        }
        // per-wave LDS slice + same-wave ordering: no barrier needed
        int e2 = 0;
        for (; e2 + 4 <= m; e2 += 4) {
            int s0 = s_src[wid][e2],     s1 = s_src[wid][e2 + 1];
            int s2 = s_src[wid][e2 + 2], s3 = s_src[wid][e2 + 3];
            float4 w0 = *reinterpret_cast<const float4*>(s_alpha[wid][e2]);
            float4 w1 = *reinterpret_cast<const float4*>(s_alpha[wid][e2 + 1]);
            float4 w2 = *reinterpret_cast<const float4*>(s_alpha[wid][e2 + 2]);
            float4 w3 = *reinterpret_cast<const float4*>(s_alpha[wid][e2 + 3]);
            uint2 v0 = embq[(size_t)s0 * 64 + lane];
            uint2 v1 = embq[(size_t)s1 * 64 + lane];
            uint2 v2 = embq[(size_t)s2 * 64 + lane];
            uint2 v3 = embq[(size_t)s3 * 64 + lane];
            EFMA(w0, v0); EFMA(w1, v1); EFMA(w2, v2); EFMA(w3, v3);
        }
        for (; e2 < m; ++e2) {
            int s0 = s_src[wid][e2];
            float4 w0 = *reinterpret_cast<const float4*>(s_alpha[wid][e2]);
            uint2 v0 = embq[(size_t)s0 * 64 + lane];
            EFMA(w0, v0);
        }
    }

    float i0 = 1.f / (den0 + 1e-16f), i1 = 1.f / (den1 + 1e-16f);
    float i2 = 1.f / (den2 + 1e-16f), i3 = 1.f / (den3 + 1e-16f);
    size_t base = (size_t)n * 256 + lane;       // uint2 units; head stride 64
    uint2 o;
    o.x = (unsigned)f2bf(a00 * i0) | ((unsigned)f2bf(a01 * i0) << 16);
    o.y = (unsigned)f2bf(a02 * i0) | ((unsigned)f2bf(a03 * i0) << 16);
    aggn[base] = o;
    o.x = (unsigned)f2bf(a10 * i1) | ((unsigned)f2bf(a11 * i1) << 16);
    o.y = (unsigned)f2bf(a12 * i1) | ((unsigned)f2bf(a13 * i1) << 16);
    aggn[base + 64] = o;
    o.x = (unsigned)f2bf(a20 * i2) | ((unsigned)f2bf(a21 * i2) << 16);
    o.y = (unsigned)f2bf(a22 * i2) | ((unsigned)f2bf(a23 * i2) << 16);
    aggn[base + 128] = o;
    o.x = (unsigned)f2bf(a30 * i3) | ((unsigned)f2bf(a31 * i3) << 16);
    o.y = (unsigned)f2bf(a32 * i3) | ((unsigned)f2bf(a33 * i3) << 16);
    aggn[base + 192] = o;
}

// ---------------------------------------------------------------------------
// bf16 MFMA GEMM with strides + z-batching (128x128 tile, BK=64, 4 waves,
// 16x16x32 MFMA, both-sides XOR swizzle).
template<int K, bool BIAS, bool OUT_BF16>
__global__ __launch_bounds__(256) void gemm_bf16(
        const unsigned short* __restrict__ A, int lda, size_t aStrideZ,
        const unsigned short* __restrict__ BT, int ldb, size_t bStrideZ,
        const float* __restrict__ bias,
        unsigned short* __restrict__ Cb, float* __restrict__ Cf,
        int ldc, size_t cStrideZ, int M) {
    __shared__ __align__(16) unsigned short As[128 * 64];
    __shared__ __align__(16) unsigned short Bs[128 * 64];
    int tid = threadIdx.x;
    int lane = tid & 63, w = tid >> 6;
    int bm = blockIdx.y * 128, bn = blockIdx.x * 128;
    int z = blockIdx.z;
    A  += (size_t)z * aStrideZ;
    BT += (size_t)z * bStrideZ;
    size_t cOff = (size_t)z * cStrideZ;
    int wr = w >> 1, wc = w & 1;

    f32x4 acc[4][4];
    #pragma unroll
    for (int i = 0; i < 4; ++i)
        #pragma unroll
        for (int j = 0; j < 4; ++j)
            acc[i][j] = (f32x4){0.f, 0.f, 0.f, 0.f};

    int lr = lane & 15, kb = lane >> 4;
    int q = lane & 7;

    for (int k0 = 0; k0 < K; k0 += 64) {
        #pragma unroll
        for (int p = 0; p < 4; ++p) {
            int row = p * 32 + w * 8 + (lane >> 3);
            int ce  = ((q ^ (row & 7)) << 3) + k0;
            int ob  = p * 4096 + w * 1024;
            int gr = bm + row; if (gr >= M) gr = M - 1;
            GLOAD16(A + (size_t)gr * lda + ce, (char*)As + ob);
            int gn = bn + row;
            GLOAD16(BT + (size_t)gn * ldb + ce, (char*)Bs + ob);
        }
        __syncthreads();

        #pragma unroll
        for (int kk = 0; kk < 2; ++kk) {
            bf16x8 a[4], b[4];
            #pragma unroll
            for (int i = 0; i < 4; ++i) {
                int row = wr * 64 + i * 16 + lr;
                a[i] = *reinterpret_cast<const bf16x8*>(
                    &As[row * 64 + (((kk * 4 + kb) ^ (row & 7)) << 3)]);
            }
            #pragma unroll
            for (int j = 0; j < 4; ++j) {
                int row = wc * 64 + j * 16 + lr;
                b[j] = *reinterpret_cast<const bf16x8*>(
                    &Bs[row * 64 + (((kk * 4 + kb) ^ (row & 7)) << 3)]);
            }
            #pragma unroll
            for (int i = 0; i < 4; ++i)
                #pragma unroll
                for (int j = 0; j < 4; ++j)
                    acc[i][j] = __builtin_amdgcn_mfma_f32_16x16x32_bf16(a[i], b[j], acc[i][j], 0, 0, 0);
        }
        __syncthreads();
    }

    int rg = lane >> 4;
    #pragma unroll
    for (int i = 0; i < 4; ++i) {
        #pragma unroll
        for (int r = 0; r < 4; ++r) {
            int row = bm + wr * 64 + i * 16 + rg * 4 + r;
            if (row >= M) continue;
            #pragma unroll
            for (int j = 0; j < 4; ++j) {
                int col = bn + wc * 64 + j * 16 + lr;
                float v = acc[i][j][r];
                if (BIAS) v += bias[col];
                if (OUT_BF16) Cb[(size_t)row * ldc + cOff + col] = f2bf(v);
                else          Cf[(size_t)row * ldc + cOff + col] = v;
            }
        }
    }
}

// ---------------------------------------------------------------------------
extern "C" void kernel_launch(void* const* d_in, const int* in_sizes, int n_in,
                              void* d_out, int out_size, void* d_ws, size_t ws_size,
                              hipStream_t stream) {
    const int*   edge_index  = (const int*)d_in[0];
    const float* edge_weight = (const float*)d_in[1];
    const float* emb         = (const float*)d_in[2];
    const float* W           = (const float*)d_in[3];
    const float* att_src     = (const float*)d_in[4];
    const float* att_dst     = (const float*)d_in[5];
    const float* att_edge    = (const float*)d_in[6];
    const float* W_edge      = (const float*)d_in[7];
    const float* bias        = (const float*)d_in[8];
    const float* W_out       = (const float*)d_in[9];
    const float* b_out       = (const float*)d_in[10];
    float* out = (float*)d_out;

    const int E = in_sizes[1];
    const int D = 256;
    const int N = in_sizes[2] / D;
    const int nb = (N + 255) / 256;
    const int mb = (N + 127) / 128;

    char* ws = (char*)d_ws;
    size_t off = 0;
    auto alloc = [&](size_t bytes) {
        size_t o = off;
        off += (bytes + 255) & ~(size_t)255;
        return o;
    };
    unsigned short* embb  = (unsigned short*)(ws + alloc((size_t)N * D * 2));       // [N][256]
    unsigned short* aggn  = (unsigned short*)(ws + alloc((size_t)N * 1024 * 2));    // [N][4*256]
    unsigned short* Wb    = (unsigned short*)(ws + alloc((size_t)D * HC * 2));      // [256][512]
    unsigned short* WoT   = (unsigned short*)(ws + alloc((size_t)HC * D * 2));      // [256][512]
    unsigned short* MT    = (unsigned short*)(ws + alloc((size_t)256 * 1024 * 2));  // [256][1024]
    float* watt    = (float*)(ws + alloc(2048 * 4));
    float* bc      = (float*)(ws + alloc(256 * 4));
    float* a_src   = (float*)(ws + alloc((size_t)N * 4 * 4));
    float* a_dst   = (float*)(ws + alloc((size_t)N * 4 * 4));
    float* sh      = (float*)(ws + alloc(64));
    float* ea_mean = (float*)(ws + alloc((size_t)N * 4));
    size_t zoff    = alloc((size_t)N * 4 * 3);             // wsum | cnt | fill
    float* wsum    = (float*)(ws + zoff);
    int*   cnt     = (int*)(ws + zoff + (size_t)N * 4);
    int*   fillc   = (int*)(ws + zoff + (size_t)N * 8);
    int*   offsets = (int*)(ws + alloc((size_t)(N + 1) * 4));
    int*   csr     = (int*)(ws + alloc((size_t)E * 4));
    int*   bsum    = (int*)(ws + alloc((size_t)nb * 4));
    int*   bbase   = (int*)(ws + alloc((size_t)nb * 4));
    int*   flag    = (int*)(ws + alloc(4));
    (void)ws_size; (void)n_in; (void)out_size;

    hipMemsetAsync(ws + zoff, 0, (size_t)N * 4 * 3, stream);
    detect_kernel<<<1, 256, 0, stream>>>(edge_index, E, flag);

    // weight preps
    cast_kernel<<<(D * HC / 4 + 255) / 256, 256, 0, stream>>>(W, Wb, D * HC / 4);
    castT_kernel<<<(HC * D + 255) / 256, 256, 0, stream>>>(W_out, WoT, HC, D);
    prep_kernel<<<1, 256, 0, stream>>>(W, att_src, att_dst, W_edge, att_edge,
                                       bias, W_out, b_out, watt, sh, bc);
    // MT[j][h*256+i] = M_h[i][j] = sum_c W[i][h*128+c] * W_out[h*128+c][j]
    gemm_bf16<128, false, true><<<dim3(2, 2, 4), 256, 0, stream>>>(
        WoT, 512, (size_t)128,
        Wb, 512, (size_t)128,
        nullptr, MT, nullptr, 1024, (size_t)256, 256);

    // fused cast + attention dots
    embcast_attdot_kernel<<<(N + 3) / 4, 256, 0, stream>>>(
        (const float4*)emb, watt, (uint2*)embb, a_src, a_dst, N);

    // edge machinery
    edge_stats_kernel<<<(E + 255) / 256, 256, 0, stream>>>(
        edge_index, edge_weight, flag, cnt, wsum, E);
    scan1_kernel<<<nb, 256, 0, stream>>>(cnt, wsum, offsets, bsum, ea_mean, N);
    scan2_kernel<<<1, 256, 0, stream>>>(bsum, bbase, nb, offsets, N, E);
    scan3_kernel<<<nb, 256, 0, stream>>>(offsets, bbase, N);
    fill_kernel<<<(E + 255) / 256, 256, 0, stream>>>(
        edge_index, flag, offsets, fillc, csr, E);

    // aggregation in emb space
    agg_kernel<<<(N + 3) / 4, 256, 0, stream>>>(
        (const uint2*)embb, a_src, a_dst, ea_mean, sh, edge_weight, edge_index,
        flag, csr, offsets, (uint2*)aggn, N);

    // out = aggn @ Mstack + bc   (single fused K=1024 GEMM)
    gemm_bf16<1024, true, false><<<dim3(2, mb, 1), 256, 0, stream>>>(
        aggn, 1024, (size_t)0,
        MT, 1024, (size_t)0,
        bc, nullptr, out, 256, (size_t)0, N);
}

// Round 6
// 353.540 us; speedup vs baseline: 1.1251x; 1.0857x over previous
//
#include <hip/hip_runtime.h>
#include <cstdint>
#include <cstddef>

#define NEG_SLOPE 0.2f
#define HC 512
#define NH 4

typedef __attribute__((ext_vector_type(8))) short bf16x8;
typedef __attribute__((ext_vector_type(4))) float f32x4;

__device__ inline float lrelu(float z) { return z > 0.f ? z : NEG_SLOPE * z; }

__device__ inline unsigned short f2bf(float f) {            // RNE
    unsigned u = __float_as_uint(f);
    u += 0x7FFFu + ((u >> 16) & 1u);
    return (unsigned short)(u >> 16);
}
__device__ inline float bflo(unsigned v) { return __uint_as_float(v << 16); }
__device__ inline float bfhi(unsigned v) { return __uint_as_float(v & 0xffff0000u); }

#define GLOAD16(gp, lp) \
    __builtin_amdgcn_global_load_lds( \
        (const __attribute__((address_space(1))) unsigned int*)(const void*)(gp), \
        (__attribute__((address_space(3))) unsigned int*)(void*)(lp), 16, 0, 0)

// ---------------------------------------------------------------------------
__global__ void detect_kernel(const int* __restrict__ ei, int E, int* __restrict__ flag) {
    __shared__ int nz;
    if (threadIdx.x == 0) nz = 0;
    __syncthreads();
    int lim = E < 256 ? E : 256;
    if (threadIdx.x < lim)
        if (ei[2 * threadIdx.x + 1] != 0) atomicOr(&nz, 1);
    __syncthreads();
    if (threadIdx.x == 0) *flag = (nz == 0) ? 1 : 0;        // 1 -> int64
}

__device__ inline int edge_read(const int* ei, int is64, size_t idx) {
    return is64 ? ei[2 * idx] : ei[idx];
}

// ---------------------------------------------------------------------------
// Combined weight prep (one kernel, 653 blocks):
//   b in [0,128)    : cast W (fp32->bf16) into Wb            (32768 float4)
//   b in [128,640)  : cast+transpose W_out -> WoT[256][512]  (131072 elems)
//   b in [640,648)  : watt[i][256], i<4: W_h@att_src_h, i>=4: W_h@att_dst_h
//   b in [648,652)  : bc partials (atomicAdd; bc pre-zeroed; +b_out once)
//   b == 652        : sh[h] = W_edge_h . att_edge_h
__global__ __launch_bounds__(256) void wprep_kernel(
        const float* __restrict__ W, const float* __restrict__ W_out,
        const float* __restrict__ att_s, const float* __restrict__ att_d,
        const float* __restrict__ W_edge, const float* __restrict__ att_edge,
        const float* __restrict__ bias, const float* __restrict__ b_out,
        unsigned short* __restrict__ Wb, unsigned short* __restrict__ WoT,
        float* __restrict__ watt, float* __restrict__ bc, float* __restrict__ sh) {
    int b = blockIdx.x, t = threadIdx.x;
    if (b < 128) {
        int i = b * 256 + t;
        float4 v = reinterpret_cast<const float4*>(W)[i];
        ushort4 o;
        o.x = f2bf(v.x); o.y = f2bf(v.y); o.z = f2bf(v.z); o.w = f2bf(v.w);
        reinterpret_cast<ushort4*>(Wb)[i] = o;
    } else if (b < 640) {
        int idx = (b - 128) * 256 + t;          // W_out[512][256]
        int r = idx >> 8, c = idx & 255;
        WoT[(size_t)c * 512 + r] = f2bf(W_out[idx]);
    } else if (b < 648) {
        int i = b - 640;                        // 0..7
        int h = i & 3;
        const float* att = (i < 4) ? att_s : att_d;
        float s = 0.f;
        for (int c = 0; c < 128; ++c)
            s += W[(size_t)t * HC + h * 128 + c] * att[h * 128 + c];
        watt[i * 256 + t] = s;
    } else if (b < 652) {
        int j0 = (b - 648) * 128;
        float s = (b == 648) ? b_out[t] : 0.f;
        for (int j = j0; j < j0 + 128; ++j)
            s += bias[j] * W_out[(size_t)j * 256 + t];
        atomicAdd(&bc[t], s);
    } else {
        if (t < NH) {
            float s = 0.f;
            for (int c = 0; c < 128; ++c)
                s += W_edge[t * 128 + c] * att_edge[t * 128 + c];
            sh[t] = s;
        }
    }
}

// ---------------------------------------------------------------------------
// Fused: bf16-cast emb + a_src/a_dst dots. 4 nodes per wave, 16 per block.
__global__ __launch_bounds__(256) void embcast_attdot_kernel(
        const float4* __restrict__ embf4, const float* __restrict__ watt,
        uint2* __restrict__ embq, float* __restrict__ a_src,
        float* __restrict__ a_dst, int N) {
    __shared__ __align__(16) float sw[8][256];
    int t = threadIdx.x;
    #pragma unroll
    for (int i = 0; i < 8; ++i) sw[i][t] = watt[i * 256 + t];
    __syncthreads();
    int wid = t >> 6, lane = t & 63;
    #pragma unroll
    for (int j = 0; j < 4; ++j) {
        int n = blockIdx.x * 16 + wid * 4 + j;
        if (n >= N) break;                      // wave-uniform
        float4 v = embf4[(size_t)n * 64 + lane];
        uint2 o;
        o.x = (unsigned)f2bf(v.x) | ((unsigned)f2bf(v.y) << 16);
        o.y = (unsigned)f2bf(v.z) | ((unsigned)f2bf(v.w) << 16);
        embq[(size_t)n * 64 + lane] = o;
        float r[8];
        #pragma unroll
        for (int i = 0; i < 8; ++i) {
            float4 wv = *reinterpret_cast<const float4*>(&sw[i][lane * 4]);
            r[i] = v.x * wv.x + v.y * wv.y + v.z * wv.z + v.w * wv.w;
        }
        #pragma unroll
        for (int off = 32; off > 0; off >>= 1) {
            #pragma unroll
            for (int i = 0; i < 8; ++i) r[i] += __shfl_xor(r[i], off);
        }
        if (lane == 0) {
            size_t bofs = (size_t)n * 4;
            a_src[bofs + 0] = r[0]; a_src[bofs + 1] = r[1];
            a_src[bofs + 2] = r[2]; a_src[bofs + 3] = r[3];
            a_dst[bofs + 0] = r[4]; a_dst[bofs + 1] = r[5];
            a_dst[bofs + 2] = r[6]; a_dst[bofs + 3] = r[7];
        }
    }
}

// ---------------------------------------------------------------------------
__global__ __launch_bounds__(256) void edge_stats_kernel(
        const int* __restrict__ ei, const float* __restrict__ ew,
        const int* __restrict__ flag, int* __restrict__ cnt,
        float* __restrict__ wsum, int E) {
    int e = blockIdx.x * 256 + threadIdx.x;
    if (e >= E) return;
    int is64 = *flag;
    int d = edge_read(ei, is64, (size_t)E + e);
    atomicAdd(&cnt[d], 1);
    atomicAdd(&wsum[d], ew[e]);
}

// ---------------------------------------------------------------------------
__global__ __launch_bounds__(256) void scan1_kernel(
        const int* __restrict__ cnt, const float* __restrict__ wsum,
        int* __restrict__ offsets, int* __restrict__ bsum,
        float* __restrict__ ea_mean, int N) {
    int b = blockIdx.x, t = threadIdx.x, i = b * 256 + t;
    int v = (i < N) ? cnt[i] : 0;
    if (i < N) ea_mean[i] = wsum[i] / fmaxf((float)v, 1.f);
    int lane = t & 63, w = t >> 6;
    int s = v;
    #pragma unroll
    for (int o = 1; o < 64; o <<= 1) {
        int u = __shfl_up(s, o);
        if (lane >= o) s += u;
    }
    __shared__ int ws_[4];
    if (lane == 63) ws_[w] = s;
    __syncthreads();
    int base = 0;
    for (int k = 0; k < 4; ++k) if (k < w) base += ws_[k];
    if (i < N) offsets[i] = base + s - v;
    if (t == 0) bsum[b] = ws_[0] + ws_[1] + ws_[2] + ws_[3];
}

__global__ __launch_bounds__(256) void scan2_kernel(
        const int* __restrict__ bsum, int* __restrict__ bbase, int nb,
        int* __restrict__ offsets, int N, int E) {
    int t = threadIdx.x;
    int v = (t < nb) ? bsum[t] : 0;
    int lane = t & 63, w = t >> 6;
    int s = v;
    #pragma unroll
    for (int o = 1; o < 64; o <<= 1) {
        int u = __shfl_up(s, o);
        if (lane >= o) s += u;
    }
    __shared__ int ws_[4];
    if (lane == 63) ws_[w] = s;
    __syncthreads();
    int base = 0;
    for (int k = 0; k < 4; ++k) if (k < w) base += ws_[k];
    if (t < nb) bbase[t] = base + s - v;
    if (t == 0) offsets[N] = E;
}

__global__ __launch_bounds__(256) void scan3_kernel(
        int* __restrict__ offsets, const int* __restrict__ bbase, int N) {
    int i = blockIdx.x * 256 + threadIdx.x;
    if (i < N) offsets[i] += bbase[blockIdx.x];
}

// ---------------------------------------------------------------------------
__global__ __launch_bounds__(256) void fill_kernel(
        const int* __restrict__ ei, const int* __restrict__ flag,
        const int* __restrict__ offsets, int* __restrict__ fill,
        int* __restrict__ csr, int E) {
    int e = blockIdx.x * 256 + threadIdx.x;
    if (e >= E) return;
    int is64 = *flag;
    int d = edge_read(ei, is64, (size_t)E + e);
    int pos = offsets[d] + atomicAdd(&fill[d], 1);
    csr[pos] = e;
}

// ---------------------------------------------------------------------------
#define EFMA(W_, V_) { \
    float e0_ = bflo(V_.x), e1_ = bfhi(V_.x), e2_ = bflo(V_.y), e3_ = bfhi(V_.y); \
    a00 += W_.x * e0_; a01 += W_.x * e1_; a02 += W_.x * e2_; a03 += W_.x * e3_; \
    a10 += W_.y * e0_; a11 += W_.y * e1_; a12 += W_.y * e2_; a13 += W_.y * e3_; \
    a20 += W_.z * e0_; a21 += W_.z * e1_; a22 += W_.z * e2_; a23 += W_.z * e3_; \
    a30 += W_.w * e0_; a31 += W_.w * e1_; a32 += W_.w * e2_; a33 += W_.w * e3_; \
    den0 += W_.x; den1 += W_.y; den2 += W_.z; den3 += W_.w; }

// One WAVE per dst node, aggregating in EMB space. Lane owns 4 dims (uint2).
// Unroll-2 (R4-proven: 36 VGPR, ~63% occupancy; unroll-4 regressed via VGPR).
__global__ __launch_bounds__(256) void agg_kernel(
        const uint2* __restrict__ embq, const float* __restrict__ a_src,
        const float* __restrict__ a_dst, const float* __restrict__ ea_mean,
        const float* __restrict__ sh, const float* __restrict__ ew,
        const int* __restrict__ ei, const int* __restrict__ flag,
        const int* __restrict__ csr, const int* __restrict__ offsets,
        uint2* __restrict__ aggn, int N) {
    int wid = threadIdx.x >> 6, lane = threadIdx.x & 63;
    int n = blockIdx.x * 4 + wid;
    if (n >= N) return;
    int is64 = *flag;
    int beg = offsets[n], end = offsets[n + 1];

    __shared__ int s_src[4][64];
    __shared__ __align__(16) float s_alpha[4][64][4];

    float ad0 = a_dst[(size_t)n * 4 + 0], ad1 = a_dst[(size_t)n * 4 + 1];
    float ad2 = a_dst[(size_t)n * 4 + 2], ad3 = a_dst[(size_t)n * 4 + 3];
    float sh0 = sh[0], sh1 = sh[1], sh2 = sh[2], sh3 = sh[3];
    float eam = ea_mean[n];
    float es0 = __expf(lrelu(a_src[(size_t)n * 4 + 0] + ad0 + eam * sh0));
    float es1 = __expf(lrelu(a_src[(size_t)n * 4 + 1] + ad1 + eam * sh1));
    float es2 = __expf(lrelu(a_src[(size_t)n * 4 + 2] + ad2 + eam * sh2));
    float es3 = __expf(lrelu(a_src[(size_t)n * 4 + 3] + ad3 + eam * sh3));

    uint2 xv = embq[(size_t)n * 64 + lane];     // self loop row
    float d0 = bflo(xv.x), d1 = bfhi(xv.x), d2 = bflo(xv.y), d3 = bfhi(xv.y);

    float a00 = es0 * d0, a01 = es0 * d1, a02 = es0 * d2, a03 = es0 * d3;
    float a10 = es1 * d0, a11 = es1 * d1, a12 = es1 * d2, a13 = es1 * d3;
    float a20 = es2 * d0, a21 = es2 * d1, a22 = es2 * d2, a23 = es2 * d3;
    float a30 = es3 * d0, a31 = es3 * d1, a32 = es3 * d2, a33 = es3 * d3;
    float den0 = es0, den1 = es1, den2 = es2, den3 = es3;

    for (int cb = beg; cb < end; cb += 64) {
        int m = end - cb; if (m > 64) m = 64;
        if (lane < m) {
            int e = csr[cb + lane];
            int s = edge_read(ei, is64, (size_t)e);
            float wgt = ew[e];
            s_src[wid][lane] = s;
            float4 as4 = *reinterpret_cast<const float4*>(&a_src[(size_t)s * 4]);
            s_alpha[wid][lane][0] = __expf(lrelu(as4.x + ad0 + wgt * sh0));
            s_alpha[wid][lane][1] = __expf(lrelu(as4.y + ad1 + wgt * sh1));
            s_alpha[wid][lane][2] = __expf(lrelu(as4.z + ad2 + wgt * sh2));
            s_alpha[wid][lane][3] = __expf(lrelu(as4.w + ad3 + wgt * sh3));
        }
        // per-wave LDS slice + same-wave ordering: no barrier needed
        int e2 = 0;
        for (; e2 + 2 <= m; e2 += 2) {
            int s0 = s_src[wid][e2], s1 = s_src[wid][e2 + 1];
            float4 w0 = *reinterpret_cast<const float4*>(s_alpha[wid][e2]);
            float4 w1 = *reinterpret_cast<const float4*>(s_alpha[wid][e2 + 1]);
            uint2 v0 = embq[(size_t)s0 * 64 + lane];
            uint2 v1 = embq[(size_t)s1 * 64 + lane];
            EFMA(w0, v0); EFMA(w1, v1);
        }
        if (e2 < m) {
            int s0 = s_src[wid][e2];
            float4 w0 = *reinterpret_cast<const float4*>(s_alpha[wid][e2]);
            uint2 v0 = embq[(size_t)s0 * 64 + lane];
            EFMA(w0, v0);
        }
    }

    float i0 = 1.f / (den0 + 1e-16f), i1 = 1.f / (den1 + 1e-16f);
    float i2 = 1.f / (den2 + 1e-16f), i3 = 1.f / (den3 + 1e-16f);
    size_t base = (size_t)n * 256 + lane;       // uint2 units; head stride 64
    uint2 o;
    o.x = (unsigned)f2bf(a00 * i0) | ((unsigned)f2bf(a01 * i0) << 16);
    o.y = (unsigned)f2bf(a02 * i0) | ((unsigned)f2bf(a03 * i0) << 16);
    aggn[base] = o;
    o.x = (unsigned)f2bf(a10 * i1) | ((unsigned)f2bf(a11 * i1) << 16);
    o.y = (unsigned)f2bf(a12 * i1) | ((unsigned)f2bf(a13 * i1) << 16);
    aggn[base + 64] = o;
    o.x = (unsigned)f2bf(a20 * i2) | ((unsigned)f2bf(a21 * i2) << 16);
    o.y = (unsigned)f2bf(a22 * i2) | ((unsigned)f2bf(a23 * i2) << 16);
    aggn[base + 128] = o;
    o.x = (unsigned)f2bf(a30 * i3) | ((unsigned)f2bf(a31 * i3) << 16);
    o.y = (unsigned)f2bf(a32 * i3) | ((unsigned)f2bf(a33 * i3) << 16);
    aggn[base + 192] = o;
}

// ---------------------------------------------------------------------------
// bf16 MFMA GEMM with strides + z-batching (128x128 tile, BK=64, 4 waves,
// 16x16x32 MFMA, both-sides XOR swizzle).
template<int K, bool BIAS, bool OUT_BF16>
__global__ __launch_bounds__(256) void gemm_bf16(
        const unsigned short* __restrict__ A, int lda, size_t aStrideZ,
        const unsigned short* __restrict__ BT, int ldb, size_t bStrideZ,
        const float* __restrict__ bias,
        unsigned short* __restrict__ Cb, float* __restrict__ Cf,
        int ldc, size_t cStrideZ, int M) {
    __shared__ __align__(16) unsigned short As[128 * 64];
    __shared__ __align__(16) unsigned short Bs[128 * 64];
    int tid = threadIdx.x;
    int lane = tid & 63, w = tid >> 6;
    int bm = blockIdx.y * 128, bn = blockIdx.x * 128;
    int z = blockIdx.z;
    A  += (size_t)z * aStrideZ;
    BT += (size_t)z * bStrideZ;
    size_t cOff = (size_t)z * cStrideZ;
    int wr = w >> 1, wc = w & 1;

    f32x4 acc[4][4];
    #pragma unroll
    for (int i = 0; i < 4; ++i)
        #pragma unroll
        for (int j = 0; j < 4; ++j)
            acc[i][j] = (f32x4){0.f, 0.f, 0.f, 0.f};

    int lr = lane & 15, kb = lane >> 4;
    int q = lane & 7;

    for (int k0 = 0; k0 < K; k0 += 64) {
        #pragma unroll
        for (int p = 0; p < 4; ++p) {
            int row = p * 32 + w * 8 + (lane >> 3);
            int ce  = ((q ^ (row & 7)) << 3) + k0;
            int ob  = p * 4096 + w * 1024;
            int gr = bm + row; if (gr >= M) gr = M - 1;
            GLOAD16(A + (size_t)gr * lda + ce, (char*)As + ob);
            int gn = bn + row;
            GLOAD16(BT + (size_t)gn * ldb + ce, (char*)Bs + ob);
        }
        __syncthreads();

        #pragma unroll
        for (int kk = 0; kk < 2; ++kk) {
            bf16x8 a[4], b[4];
            #pragma unroll
            for (int i = 0; i < 4; ++i) {
                int row = wr * 64 + i * 16 + lr;
                a[i] = *reinterpret_cast<const bf16x8*>(
                    &As[row * 64 + (((kk * 4 + kb) ^ (row & 7)) << 3)]);
            }
            #pragma unroll
            for (int j = 0; j < 4; ++j) {
                int row = wc * 64 + j * 16 + lr;
                b[j] = *reinterpret_cast<const bf16x8*>(
                    &Bs[row * 64 + (((kk * 4 + kb) ^ (row & 7)) << 3)]);
            }
            #pragma unroll
            for (int i = 0; i < 4; ++i)
                #pragma unroll
                for (int j = 0; j < 4; ++j)
                    acc[i][j] = __builtin_amdgcn_mfma_f32_16x16x32_bf16(a[i], b[j], acc[i][j], 0, 0, 0);
        }
        __syncthreads();
    }

    int rg = lane >> 4;
    #pragma unroll
    for (int i = 0; i < 4; ++i) {
        #pragma unroll
        for (int r = 0; r < 4; ++r) {
            int row = bm + wr * 64 + i * 16 + rg * 4 + r;
            if (row >= M) continue;
            #pragma unroll
            for (int j = 0; j < 4; ++j) {
                int col = bn + wc * 64 + j * 16 + lr;
                float v = acc[i][j][r];
                if (BIAS) v += bias[col];
                if (OUT_BF16) Cb[(size_t)row * ldc + cOff + col] = f2bf(v);
                else          Cf[(size_t)row * ldc + cOff + col] = v;
            }
        }
    }
}

// ---------------------------------------------------------------------------
extern "C" void kernel_launch(void* const* d_in, const int* in_sizes, int n_in,
                              void* d_out, int out_size, void* d_ws, size_t ws_size,
                              hipStream_t stream) {
    const int*   edge_index  = (const int*)d_in[0];
    const float* edge_weight = (const float*)d_in[1];
    const float* emb         = (const float*)d_in[2];
    const float* W           = (const float*)d_in[3];
    const float* att_src     = (const float*)d_in[4];
    const float* att_dst     = (const float*)d_in[5];
    const float* att_edge    = (const float*)d_in[6];
    const float* W_edge      = (const float*)d_in[7];
    const float* bias        = (const float*)d_in[8];
    const float* W_out       = (const float*)d_in[9];
    const float* b_out       = (const float*)d_in[10];
    float* out = (float*)d_out;

    const int E = in_sizes[1];
    const int D = 256;
    const int N = in_sizes[2] / D;
    const int nb = (N + 255) / 256;
    const int mb = (N + 127) / 128;

    char* ws = (char*)d_ws;
    size_t off = 0;
    auto alloc = [&](size_t bytes) {
        size_t o = off;
        off += (bytes + 255) & ~(size_t)255;
        return o;
    };
    unsigned short* embb  = (unsigned short*)(ws + alloc((size_t)N * D * 2));       // [N][256]
    unsigned short* aggn  = (unsigned short*)(ws + alloc((size_t)N * 1024 * 2));    // [N][4*256]
    unsigned short* Wb    = (unsigned short*)(ws + alloc((size_t)D * HC * 2));      // [256][512]
    unsigned short* WoT   = (unsigned short*)(ws + alloc((size_t)HC * D * 2));      // [256][512]
    unsigned short* MT    = (unsigned short*)(ws + alloc((size_t)256 * 1024 * 2));  // [256][1024]
    float* watt    = (float*)(ws + alloc(2048 * 4));
    float* a_src   = (float*)(ws + alloc((size_t)N * 4 * 4));
    float* a_dst   = (float*)(ws + alloc((size_t)N * 4 * 4));
    float* sh      = (float*)(ws + alloc(64));
    float* ea_mean = (float*)(ws + alloc((size_t)N * 4));
    size_t zoff    = alloc((size_t)N * 4 * 3 + 1024);      // wsum | cnt | fill | bc
    float* wsum    = (float*)(ws + zoff);
    int*   cnt     = (int*)(ws + zoff + (size_t)N * 4);
    int*   fillc   = (int*)(ws + zoff + (size_t)N * 8);
    float* bc      = (float*)(ws + zoff + (size_t)N * 12);
    int*   offsets = (int*)(ws + alloc((size_t)(N + 1) * 4));
    int*   csr     = (int*)(ws + alloc((size_t)E * 4));
    int*   bsum    = (int*)(ws + alloc((size_t)nb * 4));
    int*   bbase   = (int*)(ws + alloc((size_t)nb * 4));
    int*   flag    = (int*)(ws + alloc(4));
    (void)ws_size; (void)n_in; (void)out_size;

    hipMemsetAsync(ws + zoff, 0, (size_t)N * 4 * 3 + 1024, stream);
    detect_kernel<<<1, 256, 0, stream>>>(edge_index, E, flag);

    // combined weight prep (casts + watt + bc + sh)
    wprep_kernel<<<653, 256, 0, stream>>>(W, W_out, att_src, att_dst, W_edge,
                                          att_edge, bias, b_out, Wb, WoT,
                                          watt, bc, sh);
    // MT[j][h*256+i] = M_h[i][j] = sum_c W[i][h*128+c] * W_out[h*128+c][j]
    gemm_bf16<128, false, true><<<dim3(2, 2, 4), 256, 0, stream>>>(
        WoT, 512, (size_t)128,
        Wb, 512, (size_t)128,
        nullptr, MT, nullptr, 1024, (size_t)256, 256);

    // fused cast + attention dots
    embcast_attdot_kernel<<<(N + 15) / 16, 256, 0, stream>>>(
        (const float4*)emb, watt, (uint2*)embb, a_src, a_dst, N);

    // edge machinery
    edge_stats_kernel<<<(E + 255) / 256, 256, 0, stream>>>(
        edge_index, edge_weight, flag, cnt, wsum, E);
    scan1_kernel<<<nb, 256, 0, stream>>>(cnt, wsum, offsets, bsum, ea_mean, N);
    scan2_kernel<<<1, 256, 0, stream>>>(bsum, bbase, nb, offsets, N, E);
    scan3_kernel<<<nb, 256, 0, stream>>>(offsets, bbase, N);
    fill_kernel<<<(E + 255) / 256, 256, 0, stream>>>(
        edge_index, flag, offsets, fillc, csr, E);

    // aggregation in emb space
    agg_kernel<<<(N + 3) / 4, 256, 0, stream>>>(
        (const uint2*)embb, a_src, a_dst, ea_mean, sh, edge_weight, edge_index,
        flag, csr, offsets, (uint2*)aggn, N);

    // out = aggn @ Mstack + bc   (single fused K=1024 GEMM)
    gemm_bf16<1024, true, false><<<dim3(2, mb, 1), 256, 0, stream>>>(
        aggn, 1024, (size_t)0,
        MT, 1024, (size_t)0,
        bc, nullptr, out, 256, (size_t)0, N);
}

// Round 7
// 330.239 us; speedup vs baseline: 1.2044x; 1.0706x over previous
//
#include <hip/hip_runtime.h>
#include <cstdint>
#include <cstddef>

#define NEG_SLOPE 0.2f
#define HC 512
#define NH 4

typedef __attribute__((ext_vector_type(8))) short bf16x8;
typedef __attribute__((ext_vector_type(4))) float f32x4;

__device__ inline float lrelu(float z) { return z > 0.f ? z : NEG_SLOPE * z; }

__device__ inline unsigned short f2bf(float f) {            // RNE
    unsigned u = __float_as_uint(f);
    u += 0x7FFFu + ((u >> 16) & 1u);
    return (unsigned short)(u >> 16);
}
__device__ inline float bflo(unsigned v) { return __uint_as_float(v << 16); }
__device__ inline float bfhi(unsigned v) { return __uint_as_float(v & 0xffff0000u); }

#define GLOAD16(gp, lp) \
    __builtin_amdgcn_global_load_lds( \
        (const __attribute__((address_space(1))) unsigned int*)(const void*)(gp), \
        (__attribute__((address_space(3))) unsigned int*)(void*)(lp), 16, 0, 0)

__device__ inline int edge_read(const int* ei, int is64, size_t idx) {
    return is64 ? ei[2 * idx] : ei[idx];
}

// ---------------------------------------------------------------------------
// Combined weight prep + edge-layout probe (654 blocks):
//   b in [0,128)    : cast W (fp32->bf16) into Wb
//   b in [128,640)  : cast+transpose W_out -> WoT[256][512]
//   b in [640,648)  : watt[i][256], i<4: W_h@att_src_h, i>=4: W_h@att_dst_h
//   b in [648,652)  : bc partials (atomicAdd; bc pre-zeroed; +b_out once)
//   b == 652        : sh[h] = W_edge_h . att_edge_h
//   b == 653        : detect int64-vs-int32 edge_index layout -> flag
__global__ __launch_bounds__(256) void wprep_kernel(
        const float* __restrict__ W, const float* __restrict__ W_out,
        const float* __restrict__ att_s, const float* __restrict__ att_d,
        const float* __restrict__ W_edge, const float* __restrict__ att_edge,
        const float* __restrict__ bias, const float* __restrict__ b_out,
        const int* __restrict__ ei, int E,
        unsigned short* __restrict__ Wb, unsigned short* __restrict__ WoT,
        float* __restrict__ watt, float* __restrict__ bc, float* __restrict__ sh,
        int* __restrict__ flag) {
    int b = blockIdx.x, t = threadIdx.x;
    if (b < 128) {
        int i = b * 256 + t;
        float4 v = reinterpret_cast<const float4*>(W)[i];
        ushort4 o;
        o.x = f2bf(v.x); o.y = f2bf(v.y); o.z = f2bf(v.z); o.w = f2bf(v.w);
        reinterpret_cast<ushort4*>(Wb)[i] = o;
    } else if (b < 640) {
        int idx = (b - 128) * 256 + t;          // W_out[512][256]
        int r = idx >> 8, c = idx & 255;
        WoT[(size_t)c * 512 + r] = f2bf(W_out[idx]);
    } else if (b < 648) {
        int i = b - 640;                        // 0..7
        int h = i & 3;
        const float* att = (i < 4) ? att_s : att_d;
        float s = 0.f;
        for (int c = 0; c < 128; ++c)
            s += W[(size_t)t * HC + h * 128 + c] * att[h * 128 + c];
        watt[i * 256 + t] = s;
    } else if (b < 652) {
        int j0 = (b - 648) * 128;
        float s = (b == 648) ? b_out[t] : 0.f;
        for (int j = j0; j < j0 + 128; ++j)
            s += bias[j] * W_out[(size_t)j * 256 + t];
        atomicAdd(&bc[t], s);
    } else if (b == 652) {
        if (t < NH) {
            float s = 0.f;
            for (int c = 0; c < 128; ++c)
                s += W_edge[t * 128 + c] * att_edge[t * 128 + c];
            sh[t] = s;
        }
    } else {
        __shared__ int nz;
        if (t == 0) nz = 0;
        __syncthreads();
        int lim = E < 256 ? E : 256;
        if (t < lim)
            if (ei[2 * t + 1] != 0) atomicOr(&nz, 1);
        __syncthreads();
        if (t == 0) *flag = (nz == 0) ? 1 : 0;  // 1 -> int64
    }
}

// ---------------------------------------------------------------------------
// Fused: bf16-cast emb + a_src/a_dst dots. 4 nodes per wave, 16 per block.
__global__ __launch_bounds__(256) void embcast_attdot_kernel(
        const float4* __restrict__ embf4, const float* __restrict__ watt,
        uint2* __restrict__ embq, float* __restrict__ a_src,
        float* __restrict__ a_dst, int N) {
    __shared__ __align__(16) float sw[8][256];
    int t = threadIdx.x;
    #pragma unroll
    for (int i = 0; i < 8; ++i) sw[i][t] = watt[i * 256 + t];
    __syncthreads();
    int wid = t >> 6, lane = t & 63;
    #pragma unroll
    for (int j = 0; j < 4; ++j) {
        int n = blockIdx.x * 16 + wid * 4 + j;
        if (n >= N) break;                      // wave-uniform
        float4 v = embf4[(size_t)n * 64 + lane];
        uint2 o;
        o.x = (unsigned)f2bf(v.x) | ((unsigned)f2bf(v.y) << 16);
        o.y = (unsigned)f2bf(v.z) | ((unsigned)f2bf(v.w) << 16);
        embq[(size_t)n * 64 + lane] = o;
        float r[8];
        #pragma unroll
        for (int i = 0; i < 8; ++i) {
            float4 wv = *reinterpret_cast<const float4*>(&sw[i][lane * 4]);
            r[i] = v.x * wv.x + v.y * wv.y + v.z * wv.z + v.w * wv.w;
        }
        #pragma unroll
        for (int off = 32; off > 0; off >>= 1) {
            #pragma unroll
            for (int i = 0; i < 8; ++i) r[i] += __shfl_xor(r[i], off);
        }
        if (lane == 0) {
            size_t bofs = (size_t)n * 4;
            a_src[bofs + 0] = r[0]; a_src[bofs + 1] = r[1];
            a_src[bofs + 2] = r[2]; a_src[bofs + 3] = r[3];
            a_dst[bofs + 0] = r[4]; a_dst[bofs + 1] = r[5];
            a_dst[bofs + 2] = r[6]; a_dst[bofs + 3] = r[7];
        }
    }
}

// ---------------------------------------------------------------------------
__global__ __launch_bounds__(256) void edge_stats_kernel(
        const int* __restrict__ ei, const float* __restrict__ ew,
        const int* __restrict__ flag, int* __restrict__ cnt,
        float* __restrict__ wsum, int E) {
    int e = blockIdx.x * 256 + threadIdx.x;
    if (e >= E) return;
    int is64 = *flag;
    int d = edge_read(ei, is64, (size_t)E + e);
    atomicAdd(&cnt[d], 1);
    atomicAdd(&wsum[d], ew[e]);
}

// ---------------------------------------------------------------------------
__global__ __launch_bounds__(256) void scan1_kernel(
        const int* __restrict__ cnt, const float* __restrict__ wsum,
        int* __restrict__ offsets, int* __restrict__ bsum,
        float* __restrict__ ea_mean, int N) {
    int b = blockIdx.x, t = threadIdx.x, i = b * 256 + t;
    int v = (i < N) ? cnt[i] : 0;
    if (i < N) ea_mean[i] = wsum[i] / fmaxf((float)v, 1.f);
    int lane = t & 63, w = t >> 6;
    int s = v;
    #pragma unroll
    for (int o = 1; o < 64; o <<= 1) {
        int u = __shfl_up(s, o);
        if (lane >= o) s += u;
    }
    __shared__ int ws_[4];
    if (lane == 63) ws_[w] = s;
    __syncthreads();
    int base = 0;
    for (int k = 0; k < 4; ++k) if (k < w) base += ws_[k];
    if (i < N) offsets[i] = base + s - v;
    if (t == 0) bsum[b] = ws_[0] + ws_[1] + ws_[2] + ws_[3];
}

__global__ __launch_bounds__(256) void scan2_kernel(
        const int* __restrict__ bsum, int* __restrict__ bbase, int nb) {
    int t = threadIdx.x;
    int v = (t < nb) ? bsum[t] : 0;
    int lane = t & 63, w = t >> 6;
    int s = v;
    #pragma unroll
    for (int o = 1; o < 64; o <<= 1) {
        int u = __shfl_up(s, o);
        if (lane >= o) s += u;
    }
    __shared__ int ws_[4];
    if (lane == 63) ws_[w] = s;
    __syncthreads();
    int base = 0;
    for (int k = 0; k < 4; ++k) if (k < w) base += ws_[k];
    if (t < nb) bbase[t] = base + s - v;
}

// ---------------------------------------------------------------------------
__global__ __launch_bounds__(256) void fill_kernel(
        const int* __restrict__ ei, const int* __restrict__ flag,
        const int* __restrict__ offsets, const int* __restrict__ bbase,
        int* __restrict__ fill, int* __restrict__ csr, int E) {
    int e = blockIdx.x * 256 + threadIdx.x;
    if (e >= E) return;
    int is64 = *flag;
    int d = edge_read(ei, is64, (size_t)E + e);
    int pos = offsets[d] + bbase[d >> 8] + atomicAdd(&fill[d], 1);
    csr[pos] = e;
}

// ---------------------------------------------------------------------------
#define EFMA(W_, V_) { \
    float e0_ = bflo(V_.x), e1_ = bfhi(V_.x), e2_ = bflo(V_.y), e3_ = bfhi(V_.y); \
    a00 += W_.x * e0_; a01 += W_.x * e1_; a02 += W_.x * e2_; a03 += W_.x * e3_; \
    a10 += W_.y * e0_; a11 += W_.y * e1_; a12 += W_.y * e2_; a13 += W_.y * e3_; \
    a20 += W_.z * e0_; a21 += W_.z * e1_; a22 += W_.z * e2_; a23 += W_.z * e3_; \
    a30 += W_.w * e0_; a31 += W_.w * e1_; a32 += W_.w * e2_; a33 += W_.w * e3_; \
    den0 += W_.x; den1 += W_.y; den2 += W_.z; den3 += W_.w; }

// One WAVE per dst node, aggregating in EMB space. Lane owns 4 dims (uint2).
// Unroll-2 (36 VGPR; unroll-4 regressed via occupancy).
__global__ __launch_bounds__(256) void agg_kernel(
        const uint2* __restrict__ embq, const float* __restrict__ a_src,
        const float* __restrict__ a_dst, const float* __restrict__ ea_mean,
        const float* __restrict__ sh, const float* __restrict__ ew,
        const int* __restrict__ ei, const int* __restrict__ flag,
        const int* __restrict__ csr, const int* __restrict__ offsets,
        const int* __restrict__ bbase, uint2* __restrict__ aggn, int N, int E) {
    int wid = threadIdx.x >> 6, lane = threadIdx.x & 63;
    int n = blockIdx.x * 4 + wid;
    if (n >= N) return;
    int is64 = *flag;
    int beg = offsets[n] + bbase[n >> 8];
    int end = (n + 1 < N) ? offsets[n + 1] + bbase[(n + 1) >> 8] : E;

    __shared__ int s_src[4][64];
    __shared__ __align__(16) float s_alpha[4][64][4];

    float ad0 = a_dst[(size_t)n * 4 + 0], ad1 = a_dst[(size_t)n * 4 + 1];
    float ad2 = a_dst[(size_t)n * 4 + 2], ad3 = a_dst[(size_t)n * 4 + 3];
    float sh0 = sh[0], sh1 = sh[1], sh2 = sh[2], sh3 = sh[3];
    float eam = ea_mean[n];
    float es0 = __expf(lrelu(a_src[(size_t)n * 4 + 0] + ad0 + eam * sh0));
    float es1 = __expf(lrelu(a_src[(size_t)n * 4 + 1] + ad1 + eam * sh1));
    float es2 = __expf(lrelu(a_src[(size_t)n * 4 + 2] + ad2 + eam * sh2));
    float es3 = __expf(lrelu(a_src[(size_t)n * 4 + 3] + ad3 + eam * sh3));

    uint2 xv = embq[(size_t)n * 64 + lane];     // self loop row
    float d0 = bflo(xv.x), d1 = bfhi(xv.x), d2 = bflo(xv.y), d3 = bfhi(xv.y);

    float a00 = es0 * d0, a01 = es0 * d1, a02 = es0 * d2, a03 = es0 * d3;
    float a10 = es1 * d0, a11 = es1 * d1, a12 = es1 * d2, a13 = es1 * d3;
    float a20 = es2 * d0, a21 = es2 * d1, a22 = es2 * d2, a23 = es2 * d3;
    float a30 = es3 * d0, a31 = es3 * d1, a32 = es3 * d2, a33 = es3 * d3;
    float den0 = es0, den1 = es1, den2 = es2, den3 = es3;

    for (int cb = beg; cb < end; cb += 64) {
        int m = end - cb; if (m > 64) m = 64;
        if (lane < m) {
            int e = csr[cb + lane];
            int s = edge_read(ei, is64, (size_t)e);
            float wgt = ew[e];
            s_src[wid][lane] = s;
            float4 as4 = *reinterpret_cast<const float4*>(&a_src[(size_t)s * 4]);
            s_alpha[wid][lane][0] = __expf(lrelu(as4.x + ad0 + wgt * sh0));
            s_alpha[wid][lane][1] = __expf(lrelu(as4.y + ad1 + wgt * sh1));
            s_alpha[wid][lane][2] = __expf(lrelu(as4.z + ad2 + wgt * sh2));
            s_alpha[wid][lane][3] = __expf(lrelu(as4.w + ad3 + wgt * sh3));
        }
        // per-wave LDS slice + same-wave ordering: no barrier needed
        int e2 = 0;
        for (; e2 + 2 <= m; e2 += 2) {
            int s0 = s_src[wid][e2], s1 = s_src[wid][e2 + 1];
            float4 w0 = *reinterpret_cast<const float4*>(s_alpha[wid][e2]);
            float4 w1 = *reinterpret_cast<const float4*>(s_alpha[wid][e2 + 1]);
            uint2 v0 = embq[(size_t)s0 * 64 + lane];
            uint2 v1 = embq[(size_t)s1 * 64 + lane];
            EFMA(w0, v0); EFMA(w1, v1);
        }
        if (e2 < m) {
            int s0 = s_src[wid][e2];
            float4 w0 = *reinterpret_cast<const float4*>(s_alpha[wid][e2]);
            uint2 v0 = embq[(size_t)s0 * 64 + lane];
            EFMA(w0, v0);
        }
    }

    float i0 = 1.f / (den0 + 1e-16f), i1 = 1.f / (den1 + 1e-16f);
    float i2 = 1.f / (den2 + 1e-16f), i3 = 1.f / (den3 + 1e-16f);
    size_t base = (size_t)n * 256 + lane;       // uint2 units; head stride 64
    uint2 o;
    o.x = (unsigned)f2bf(a00 * i0) | ((unsigned)f2bf(a01 * i0) << 16);
    o.y = (unsigned)f2bf(a02 * i0) | ((unsigned)f2bf(a03 * i0) << 16);
    aggn[base] = o;
    o.x = (unsigned)f2bf(a10 * i1) | ((unsigned)f2bf(a11 * i1) << 16);
    o.y = (unsigned)f2bf(a12 * i1) | ((unsigned)f2bf(a13 * i1) << 16);
    aggn[base + 64] = o;
    o.x = (unsigned)f2bf(a20 * i2) | ((unsigned)f2bf(a21 * i2) << 16);
    o.y = (unsigned)f2bf(a22 * i2) | ((unsigned)f2bf(a23 * i2) << 16);
    aggn[base + 128] = o;
    o.x = (unsigned)f2bf(a30 * i3) | ((unsigned)f2bf(a31 * i3) << 16);
    o.y = (unsigned)f2bf(a32 * i3) | ((unsigned)f2bf(a33 * i3) << 16);
    aggn[base + 192] = o;
}

// ---------------------------------------------------------------------------
// bf16 MFMA GEMM, 128x128 tile (used only for the tiny MT precompute).
template<int K, bool BIAS, bool OUT_BF16>
__global__ __launch_bounds__(256) void gemm_bf16(
        const unsigned short* __restrict__ A, int lda, size_t aStrideZ,
        const unsigned short* __restrict__ BT, int ldb, size_t bStrideZ,
        const float* __restrict__ bias,
        unsigned short* __restrict__ Cb, float* __restrict__ Cf,
        int ldc, size_t cStrideZ, int M) {
    __shared__ __align__(16) unsigned short As[128 * 64];
    __shared__ __align__(16) unsigned short Bs[128 * 64];
    int tid = threadIdx.x;
    int lane = tid & 63, w = tid >> 6;
    int bm = blockIdx.y * 128, bn = blockIdx.x * 128;
    int z = blockIdx.z;
    A  += (size_t)z * aStrideZ;
    BT += (size_t)z * bStrideZ;
    size_t cOff = (size_t)z * cStrideZ;
    int wr = w >> 1, wc = w & 1;

    f32x4 acc[4][4];
    #pragma unroll
    for (int i = 0; i < 4; ++i)
        #pragma unroll
        for (int j = 0; j < 4; ++j)
            acc[i][j] = (f32x4){0.f, 0.f, 0.f, 0.f};

    int lr = lane & 15, kb = lane >> 4;
    int q = lane & 7;

    for (int k0 = 0; k0 < K; k0 += 64) {
        #pragma unroll
        for (int p = 0; p < 4; ++p) {
            int row = p * 32 + w * 8 + (lane >> 3);
            int ce  = ((q ^ (row & 7)) << 3) + k0;
            int ob  = p * 4096 + w * 1024;
            int gr = bm + row; if (gr >= M) gr = M - 1;
            GLOAD16(A + (size_t)gr * lda + ce, (char*)As + ob);
            int gn = bn + row;
            GLOAD16(BT + (size_t)gn * ldb + ce, (char*)Bs + ob);
        }
        __syncthreads();

        #pragma unroll
        for (int kk = 0; kk < 2; ++kk) {
            bf16x8 a[4], b[4];
            #pragma unroll
            for (int i = 0; i < 4; ++i) {
                int row = wr * 64 + i * 16 + lr;
                a[i] = *reinterpret_cast<const bf16x8*>(
                    &As[row * 64 + (((kk * 4 + kb) ^ (row & 7)) << 3)]);
            }
            #pragma unroll
            for (int j = 0; j < 4; ++j) {
                int row = wc * 64 + j * 16 + lr;
                b[j] = *reinterpret_cast<const bf16x8*>(
                    &Bs[row * 64 + (((kk * 4 + kb) ^ (row & 7)) << 3)]);
            }
            #pragma unroll
            for (int i = 0; i < 4; ++i)
                #pragma unroll
                for (int j = 0; j < 4; ++j)
                    acc[i][j] = __builtin_amdgcn_mfma_f32_16x16x32_bf16(a[i], b[j], acc[i][j], 0, 0, 0);
        }
        __syncthreads();
    }

    int rg = lane >> 4;
    #pragma unroll
    for (int i = 0; i < 4; ++i) {
        #pragma unroll
        for (int r = 0; r < 4; ++r) {
            int row = bm + wr * 64 + i * 16 + rg * 4 + r;
            if (row >= M) continue;
            #pragma unroll
            for (int j = 0; j < 4; ++j) {
                int col = bn + wc * 64 + j * 16 + lr;
                float v = acc[i][j][r];
                if (BIAS) v += bias[col];
                if (OUT_BF16) Cb[(size_t)row * ldc + cOff + col] = f2bf(v);
                else          Cf[(size_t)row * ldc + cOff + col] = v;
            }
        }
    }
}

// ---------------------------------------------------------------------------
// Output GEMM: out[M][256] = aggn[M][1024] @ MT[256][1024]^T + bc.
// 128x256 tile (full N in one block -> A read exactly once), 512 threads,
// 8 waves (2 row x 4 col of 64x64), BK=64, both-sides XOR swizzle.
__global__ __launch_bounds__(512) void gemm_out_kernel(
        const unsigned short* __restrict__ A,
        const unsigned short* __restrict__ BT,
        const float* __restrict__ bias, float* __restrict__ C, int M) {
    __shared__ __align__(16) unsigned short As[128 * 64];   // 16 KB
    __shared__ __align__(16) unsigned short Bs[256 * 64];   // 32 KB
    int tid = threadIdx.x;
    int lane = tid & 63, w = tid >> 6;
    int bm = blockIdx.x * 128;
    int wr = w >> 2, wc = w & 3;

    f32x4 acc[4][4];
    #pragma unroll
    for (int i = 0; i < 4; ++i)
        #pragma unroll
        for (int j = 0; j < 4; ++j)
            acc[i][j] = (f32x4){0.f, 0.f, 0.f, 0.f};

    int lr = lane & 15, kb = lane >> 4;
    int q = lane & 7;

    for (int k0 = 0; k0 < 1024; k0 += 64) {
        {   // A: 2 phases of 64 rows (8 waves x 8 rows)
            #pragma unroll
            for (int p = 0; p < 2; ++p) {
                int row = p * 64 + w * 8 + (lane >> 3);
                int ce  = ((q ^ (row & 7)) << 3) + k0;
                int ob  = p * 8192 + w * 1024;
                int gr = bm + row; if (gr >= M) gr = M - 1;
                GLOAD16(A + (size_t)gr * 1024 + ce, (char*)As + ob);
            }
            // B: 4 phases of 64 rows
            #pragma unroll
            for (int p = 0; p < 4; ++p) {
                int row = p * 64 + w * 8 + (lane >> 3);
                int ce  = ((q ^ (row & 7)) << 3) + k0;
                int ob  = p * 8192 + w * 1024;
                GLOAD16(BT + (size_t)row * 1024 + ce, (char*)Bs + ob);
            }
        }
        __syncthreads();

        #pragma unroll
        for (int kk = 0; kk < 2; ++kk) {
            bf16x8 a[4], b[4];
            #pragma unroll
            for (int i = 0; i < 4; ++i) {
                int row = wr * 64 + i * 16 + lr;
                a[i] = *reinterpret_cast<const bf16x8*>(
                    &As[row * 64 + (((kk * 4 + kb) ^ (row & 7)) << 3)]);
            }
            #pragma unroll
            for (int j = 0; j < 4; ++j) {
                int row = wc * 64 + j * 16 + lr;
                b[j] = *reinterpret_cast<const bf16x8*>(
                    &Bs[row * 64 + (((kk * 4 + kb) ^ (row & 7)) << 3)]);
            }
            #pragma unroll
            for (int i = 0; i < 4; ++i)
                #pragma unroll
                for (int j = 0; j < 4; ++j)
                    acc[i][j] = __builtin_amdgcn_mfma_f32_16x16x32_bf16(a[i], b[j], acc[i][j], 0, 0, 0);
        }
        __syncthreads();
    }

    int rg = lane >> 4;
    #pragma unroll
    for (int i = 0; i < 4; ++i) {
        #pragma unroll
        for (int r = 0; r < 4; ++r) {
            int row = bm + wr * 64 + i * 16 + rg * 4 + r;
            if (row >= M) continue;
            #pragma unroll
            for (int j = 0; j < 4; ++j) {
                int col = wc * 64 + j * 16 + lr;
                C[(size_t)row * 256 + col] = acc[i][j][r] + bias[col];
            }
        }
    }
}

// ---------------------------------------------------------------------------
extern "C" void kernel_launch(void* const* d_in, const int* in_sizes, int n_in,
                              void* d_out, int out_size, void* d_ws, size_t ws_size,
                              hipStream_t stream) {
    const int*   edge_index  = (const int*)d_in[0];
    const float* edge_weight = (const float*)d_in[1];
    const float* emb         = (const float*)d_in[2];
    const float* W           = (const float*)d_in[3];
    const float* att_src     = (const float*)d_in[4];
    const float* att_dst     = (const float*)d_in[5];
    const float* att_edge    = (const float*)d_in[6];
    const float* W_edge      = (const float*)d_in[7];
    const float* bias        = (const float*)d_in[8];
    const float* W_out       = (const float*)d_in[9];
    const float* b_out       = (const float*)d_in[10];
    float* out = (float*)d_out;

    const int E = in_sizes[1];
    const int D = 256;
    const int N = in_sizes[2] / D;
    const int nb = (N + 255) / 256;
    const int mb = (N + 127) / 128;

    char* ws = (char*)d_ws;
    size_t off = 0;
    auto alloc = [&](size_t bytes) {
        size_t o = off;
        off += (bytes + 255) & ~(size_t)255;
        return o;
    };
    unsigned short* embb  = (unsigned short*)(ws + alloc((size_t)N * D * 2));       // [N][256]
    unsigned short* aggn  = (unsigned short*)(ws + alloc((size_t)N * 1024 * 2));    // [N][4*256]
    unsigned short* Wb    = (unsigned short*)(ws + alloc((size_t)D * HC * 2));      // [256][512]
    unsigned short* WoT   = (unsigned short*)(ws + alloc((size_t)HC * D * 2));      // [256][512]
    unsigned short* MT    = (unsigned short*)(ws + alloc((size_t)256 * 1024 * 2));  // [256][1024]
    float* watt    = (float*)(ws + alloc(2048 * 4));
    float* a_src   = (float*)(ws + alloc((size_t)N * 4 * 4));
    float* a_dst   = (float*)(ws + alloc((size_t)N * 4 * 4));
    float* sh      = (float*)(ws + alloc(64));
    float* ea_mean = (float*)(ws + alloc((size_t)N * 4));
    size_t zoff    = alloc((size_t)N * 4 * 3 + 1024);      // wsum | cnt | fill | bc
    float* wsum    = (float*)(ws + zoff);
    int*   cnt     = (int*)(ws + zoff + (size_t)N * 4);
    int*   fillc   = (int*)(ws + zoff + (size_t)N * 8);
    float* bc      = (float*)(ws + zoff + (size_t)N * 12);
    int*   offsets = (int*)(ws + alloc((size_t)(N + 1) * 4));
    int*   csr     = (int*)(ws + alloc((size_t)E * 4));
    int*   bsum    = (int*)(ws + alloc((size_t)nb * 4));
    int*   bbase   = (int*)(ws + alloc((size_t)nb * 4));
    int*   flag    = (int*)(ws + alloc(4));
    (void)ws_size; (void)n_in; (void)out_size;

    hipMemsetAsync(ws + zoff, 0, (size_t)N * 4 * 3 + 1024, stream);

    // combined weight prep (casts + watt + bc + sh + edge-layout detect)
    wprep_kernel<<<654, 256, 0, stream>>>(W, W_out, att_src, att_dst, W_edge,
                                          att_edge, bias, b_out, edge_index, E,
                                          Wb, WoT, watt, bc, sh, flag);
    // MT[j][h*256+i] = M_h[i][j] = sum_c W[i][h*128+c] * W_out[h*128+c][j]
    gemm_bf16<128, false, true><<<dim3(2, 2, 4), 256, 0, stream>>>(
        WoT, 512, (size_t)128,
        Wb, 512, (size_t)128,
        nullptr, MT, nullptr, 1024, (size_t)256, 256);

    // fused cast + attention dots
    embcast_attdot_kernel<<<(N + 15) / 16, 256, 0, stream>>>(
        (const float4*)emb, watt, (uint2*)embb, a_src, a_dst, N);

    // edge machinery
    edge_stats_kernel<<<(E + 255) / 256, 256, 0, stream>>>(
        edge_index, edge_weight, flag, cnt, wsum, E);
    scan1_kernel<<<nb, 256, 0, stream>>>(cnt, wsum, offsets, bsum, ea_mean, N);
    scan2_kernel<<<1, 256, 0, stream>>>(bsum, bbase, nb);
    fill_kernel<<<(E + 255) / 256, 256, 0, stream>>>(
        edge_index, flag, offsets, bbase, fillc, csr, E);

    // aggregation in emb space
    agg_kernel<<<(N + 3) / 4, 256, 0, stream>>>(
        (const uint2*)embb, a_src, a_dst, ea_mean, sh, edge_weight, edge_index,
        flag, csr, offsets, bbase, (uint2*)aggn, N, E);

    // out = aggn @ Mstack + bc   (A-tile read exactly once: 128x256 tile)
    gemm_out_kernel<<<mb, 512, 0, stream>>>(aggn, MT, bc, out, N);
}

// Round 8
// 322.217 us; speedup vs baseline: 1.2344x; 1.0249x over previous
//
#include <hip/hip_runtime.h>
#include <cstdint>
#include <cstddef>

#define NEG_SLOPE 0.2f
#define HC 512
#define NH 4

typedef __attribute__((ext_vector_type(8))) short bf16x8;
typedef __attribute__((ext_vector_type(4))) float f32x4;

__device__ inline float lrelu(float z) { return z > 0.f ? z : NEG_SLOPE * z; }

__device__ inline unsigned short f2bf(float f) {            // RNE
    unsigned u = __float_as_uint(f);
    u += 0x7FFFu + ((u >> 16) & 1u);
    return (unsigned short)(u >> 16);
}
__device__ inline float bflo(unsigned v) { return __uint_as_float(v << 16); }
__device__ inline float bfhi(unsigned v) { return __uint_as_float(v & 0xffff0000u); }

#define GLOAD16(gp, lp) \
    __builtin_amdgcn_global_load_lds( \
        (const __attribute__((address_space(1))) unsigned int*)(const void*)(gp), \
        (__attribute__((address_space(3))) unsigned int*)(void*)(lp), 16, 0, 0)

__device__ inline int edge_read(const int* ei, int is64, size_t idx) {
    return is64 ? ei[2 * idx] : ei[idx];
}

// ---------------------------------------------------------------------------
// Weight prep + probe + workspace zeroing (654+nzb blocks):
//   [0,128)    : cast W -> Wb bf16
//   [128,640)  : cast+transpose W_out -> WoT[256][512]
//   [640,648)  : watt[i][256] (i<4: W_h@att_src_h, else W_h@att_dst_h)
//   [648,652)  : bc4[part][256] partials of bias@W_out (+b_out in part 0)
//   652        : sh[h] = W_edge_h . att_edge_h
//   653        : detect int64-vs-int32 edge_index layout -> flag
//   [654,..)   : zero the cnt/wsum/fillc/gsum region (uint4 stores)
__global__ __launch_bounds__(256) void wprep_kernel(
        const float* __restrict__ W, const float* __restrict__ W_out,
        const float* __restrict__ att_s, const float* __restrict__ att_d,
        const float* __restrict__ W_edge, const float* __restrict__ att_edge,
        const float* __restrict__ bias, const float* __restrict__ b_out,
        const int* __restrict__ ei, int E,
        unsigned short* __restrict__ Wb, unsigned short* __restrict__ WoT,
        float* __restrict__ watt, float* __restrict__ bc4, float* __restrict__ sh,
        int* __restrict__ flag, uint4* __restrict__ zptr, int zcount) {
    int b = blockIdx.x, t = threadIdx.x;
    if (b < 128) {
        int i = b * 256 + t;
        float4 v = reinterpret_cast<const float4*>(W)[i];
        ushort4 o;
        o.x = f2bf(v.x); o.y = f2bf(v.y); o.z = f2bf(v.z); o.w = f2bf(v.w);
        reinterpret_cast<ushort4*>(Wb)[i] = o;
    } else if (b < 640) {
        int idx = (b - 128) * 256 + t;          // W_out[512][256]
        int r = idx >> 8, c = idx & 255;
        WoT[(size_t)c * 512 + r] = f2bf(W_out[idx]);
    } else if (b < 648) {
        int i = b - 640;                        // 0..7
        int h = i & 3;
        const float* att = (i < 4) ? att_s : att_d;
        float s = 0.f;
        for (int c = 0; c < 128; ++c)
            s += W[(size_t)t * HC + h * 128 + c] * att[h * 128 + c];
        watt[i * 256 + t] = s;
    } else if (b < 652) {
        int part = b - 648;                     // 0..3
        int j0 = part * 128;
        float s = (part == 0) ? b_out[t] : 0.f;
        for (int j = j0; j < j0 + 128; ++j)
            s += bias[j] * W_out[(size_t)j * 256 + t];
        bc4[part * 256 + t] = s;
    } else if (b == 652) {
        if (t < NH) {
            float s = 0.f;
            for (int c = 0; c < 128; ++c)
                s += W_edge[t * 128 + c] * att_edge[t * 128 + c];
            sh[t] = s;
        }
    } else if (b == 653) {
        __shared__ int nz;
        if (t == 0) nz = 0;
        __syncthreads();
        int lim = E < 256 ? E : 256;
        if (t < lim)
            if (ei[2 * t + 1] != 0) atomicOr(&nz, 1);
        __syncthreads();
        if (t == 0) *flag = (nz == 0) ? 1 : 0;  // 1 -> int64
    } else {
        int idx = (b - 654) * 256 + t;
        if (idx < zcount) zptr[idx] = (uint4){0u, 0u, 0u, 0u};
    }
}

// ---------------------------------------------------------------------------
// mega1: three independent post-wprep jobs in one dispatch (role by blockIdx):
//   [0,16)           : MT[j][h*256+i] = sum_c W[i][h*128+c]*W_out[h*128+c][j]
//                      (128x128 MFMA tiles; A=WoT, B=Wb, both K-contig)
//   [16,16+nEmb)     : fused bf16-cast of emb + a_src/a_dst dots
//   [16+nEmb, ...)   : edge stats (cnt/wsum atomics)
__global__ __launch_bounds__(256) void mega1_kernel(
        const unsigned short* __restrict__ WoT, const unsigned short* __restrict__ Wb,
        unsigned short* __restrict__ MT,
        const float4* __restrict__ embf4, const float* __restrict__ watt,
        uint2* __restrict__ embq, float* __restrict__ a_src,
        float* __restrict__ a_dst, int N, int nEmb,
        const int* __restrict__ ei, const float* __restrict__ ew,
        const int* __restrict__ flag, int* __restrict__ cnt,
        float* __restrict__ wsum, int E) {
    __shared__ __align__(16) char smem[32768];
    int b = blockIdx.x, t = threadIdx.x;

    if (b < 16) {
        // ---- MT tile: bm over WoT rows (j), bn over Wb rows (i), z = head
        unsigned short* As = (unsigned short*)smem;
        unsigned short* Bs = (unsigned short*)(smem + 16384);
        int lane = t & 63, w = t >> 6;
        int bn = (b & 1) * 128, bm = ((b >> 1) & 1) * 128, z = b >> 2;
        const unsigned short* A  = WoT + (size_t)z * 128;
        const unsigned short* BT = Wb  + (size_t)z * 128;
        int wr = w >> 1, wc = w & 1;

        f32x4 acc[4][4];
        #pragma unroll
        for (int i = 0; i < 4; ++i)
            #pragma unroll
            for (int j = 0; j < 4; ++j)
                acc[i][j] = (f32x4){0.f, 0.f, 0.f, 0.f};

        int lr = lane & 15, kb = lane >> 4;
        int q = lane & 7;

        for (int k0 = 0; k0 < 128; k0 += 64) {
            #pragma unroll
            for (int p = 0; p < 4; ++p) {
                int row = p * 32 + w * 8 + (lane >> 3);
                int ce  = ((q ^ (row & 7)) << 3) + k0;
                int ob  = p * 4096 + w * 1024;
                GLOAD16(A  + (size_t)(bm + row) * 512 + ce, (char*)As + ob);
                GLOAD16(BT + (size_t)(bn + row) * 512 + ce, (char*)Bs + ob);
            }
            __syncthreads();
            #pragma unroll
            for (int kk = 0; kk < 2; ++kk) {
                bf16x8 a[4], bfr[4];
                #pragma unroll
                for (int i = 0; i < 4; ++i) {
                    int row = wr * 64 + i * 16 + lr;
                    a[i] = *reinterpret_cast<const bf16x8*>(
                        &As[row * 64 + (((kk * 4 + kb) ^ (row & 7)) << 3)]);
                }
                #pragma unroll
                for (int j = 0; j < 4; ++j) {
                    int row = wc * 64 + j * 16 + lr;
                    bfr[j] = *reinterpret_cast<const bf16x8*>(
                        &Bs[row * 64 + (((kk * 4 + kb) ^ (row & 7)) << 3)]);
                }
                #pragma unroll
                for (int i = 0; i < 4; ++i)
                    #pragma unroll
                    for (int j = 0; j < 4; ++j)
                        acc[i][j] = __builtin_amdgcn_mfma_f32_16x16x32_bf16(a[i], bfr[j], acc[i][j], 0, 0, 0);
            }
            __syncthreads();
        }
        int rg = lane >> 4;
        #pragma unroll
        for (int i = 0; i < 4; ++i)
            #pragma unroll
            for (int r = 0; r < 4; ++r) {
                int row = bm + wr * 64 + i * 16 + rg * 4 + r;
                #pragma unroll
                for (int j = 0; j < 4; ++j) {
                    int col = bn + wc * 64 + j * 16 + lr;
                    MT[(size_t)row * 1024 + z * 256 + col] = f2bf(acc[i][j][r]);
                }
            }
    } else if (b < 16 + nEmb) {
        // ---- fused cast + attention dots (4 nodes/wave, 16/block)
        float (*sw)[256] = reinterpret_cast<float(*)[256]>(smem);
        #pragma unroll
        for (int i = 0; i < 8; ++i) sw[i][t] = watt[i * 256 + t];
        __syncthreads();
        int wid = t >> 6, lane = t & 63;
        int bb = b - 16;
        #pragma unroll
        for (int j = 0; j < 4; ++j) {
            int n = bb * 16 + wid * 4 + j;
            if (n >= N) break;                  // wave-uniform
            float4 v = embf4[(size_t)n * 64 + lane];
            uint2 o;
            o.x = (unsigned)f2bf(v.x) | ((unsigned)f2bf(v.y) << 16);
            o.y = (unsigned)f2bf(v.z) | ((unsigned)f2bf(v.w) << 16);
            embq[(size_t)n * 64 + lane] = o;
            float r[8];
            #pragma unroll
            for (int i = 0; i < 8; ++i) {
                float4 wv = *reinterpret_cast<const float4*>(&sw[i][lane * 4]);
                r[i] = v.x * wv.x + v.y * wv.y + v.z * wv.z + v.w * wv.w;
            }
            #pragma unroll
            for (int off = 32; off > 0; off >>= 1) {
                #pragma unroll
                for (int i = 0; i < 8; ++i) r[i] += __shfl_xor(r[i], off);
            }
            if (lane == 0) {
                size_t bofs = (size_t)n * 4;
                a_src[bofs + 0] = r[0]; a_src[bofs + 1] = r[1];
                a_src[bofs + 2] = r[2]; a_src[bofs + 3] = r[3];
                a_dst[bofs + 0] = r[4]; a_dst[bofs + 1] = r[5];
                a_dst[bofs + 2] = r[6]; a_dst[bofs + 3] = r[7];
            }
        }
    } else {
        // ---- edge stats
        int e = (b - 16 - nEmb) * 256 + t;
        if (e < E) {
            int is64 = *flag;
            int d = edge_read(ei, is64, (size_t)E + e);
            atomicAdd(&cnt[d], 1);
            atomicAdd(&wsum[d], ew[e]);
        }
    }
}

// ---------------------------------------------------------------------------
// Single-dispatch exclusive scan of cnt -> offsets via decoupled lookback.
// nb blocks (<= 256 => all co-resident on 256 CUs; spin-wait is safe).
// Also computes ea_mean. gsum must be pre-zeroed (done by wprep).
__global__ __launch_bounds__(256) void scan_kernel(
        const int* __restrict__ cnt, const float* __restrict__ wsum,
        int* __restrict__ offsets, float* __restrict__ ea_mean,
        int* __restrict__ gsum, int N, int E) {
    int b = blockIdx.x, t = threadIdx.x, i = b * 256 + t;
    int v = (i < N) ? cnt[i] : 0;
    if (i < N) ea_mean[i] = wsum[i] / fmaxf((float)v, 1.f);
    int lane = t & 63, w = t >> 6;
    int s = v;
    #pragma unroll
    for (int o = 1; o < 64; o <<= 1) {
        int u = __shfl_up(s, o);
        if (lane >= o) s += u;
    }
    __shared__ int ws_[4], ps_[4];
    if (lane == 63) ws_[w] = s;
    __syncthreads();
    int base0 = 0;
    for (int k = 0; k < 4; ++k) if (k < w) base0 += ws_[k];
    int local_ex = base0 + s - v;
    int T = ws_[0] + ws_[1] + ws_[2] + ws_[3];

    // publish own total (sentinel +1 so 0 == not ready)
    if (t == 0) {
        __threadfence();
        atomicExch(&gsum[b], T + 1);
    }
    // lookback: thread t polls predecessor t (b <= 255)
    int part = 0;
    if (t < b) {
        int g;
        do { g = atomicAdd(&gsum[t], 0); } while (g == 0);
        part = g - 1;
    }
    #pragma unroll
    for (int o = 32; o > 0; o >>= 1) part += __shfl_xor(part, o);
    if (lane == 0) ps_[w] = part;
    __syncthreads();
    int gbase = ps_[0] + ps_[1] + ps_[2] + ps_[3];
    if (i < N) offsets[i] = gbase + local_ex;
    if (b == 0 && t == 0) offsets[N] = E;
}

// ---------------------------------------------------------------------------
__global__ __launch_bounds__(256) void fill_kernel(
        const int* __restrict__ ei, const int* __restrict__ flag,
        const int* __restrict__ offsets, int* __restrict__ fill,
        int* __restrict__ csr, int E) {
    int e = blockIdx.x * 256 + threadIdx.x;
    if (e >= E) return;
    int is64 = *flag;
    int d = edge_read(ei, is64, (size_t)E + e);
    int pos = offsets[d] + atomicAdd(&fill[d], 1);
    csr[pos] = e;
}

// ---------------------------------------------------------------------------
#define EFMA(W_, V_) { \
    float e0_ = bflo(V_.x), e1_ = bfhi(V_.x), e2_ = bflo(V_.y), e3_ = bfhi(V_.y); \
    a00 += W_.x * e0_; a01 += W_.x * e1_; a02 += W_.x * e2_; a03 += W_.x * e3_; \
    a10 += W_.y * e0_; a11 += W_.y * e1_; a12 += W_.y * e2_; a13 += W_.y * e3_; \
    a20 += W_.z * e0_; a21 += W_.z * e1_; a22 += W_.z * e2_; a23 += W_.z * e3_; \
    a30 += W_.w * e0_; a31 += W_.w * e1_; a32 += W_.w * e2_; a33 += W_.w * e3_; \
    den0 += W_.x; den1 += W_.y; den2 += W_.z; den3 += W_.w; }

// One WAVE per dst node, aggregating in EMB space. Lane owns 4 dims (uint2).
// Unroll-2 (36 VGPR; unroll-4 regressed via occupancy).
__global__ __launch_bounds__(256) void agg_kernel(
        const uint2* __restrict__ embq, const float* __restrict__ a_src,
        const float* __restrict__ a_dst, const float* __restrict__ ea_mean,
        const float* __restrict__ sh, const float* __restrict__ ew,
        const int* __restrict__ ei, const int* __restrict__ flag,
        const int* __restrict__ csr, const int* __restrict__ offsets,
        uint2* __restrict__ aggn, int N) {
    int wid = threadIdx.x >> 6, lane = threadIdx.x & 63;
    int n = blockIdx.x * 4 + wid;
    if (n >= N) return;
    int is64 = *flag;
    int beg = offsets[n], end = offsets[n + 1];

    __shared__ int s_src[4][64];
    __shared__ __align__(16) float s_alpha[4][64][4];

    float ad0 = a_dst[(size_t)n * 4 + 0], ad1 = a_dst[(size_t)n * 4 + 1];
    float ad2 = a_dst[(size_t)n * 4 + 2], ad3 = a_dst[(size_t)n * 4 + 3];
    float sh0 = sh[0], sh1 = sh[1], sh2 = sh[2], sh3 = sh[3];
    float eam = ea_mean[n];
    float es0 = __expf(lrelu(a_src[(size_t)n * 4 + 0] + ad0 + eam * sh0));
    float es1 = __expf(lrelu(a_src[(size_t)n * 4 + 1] + ad1 + eam * sh1));
    float es2 = __expf(lrelu(a_src[(size_t)n * 4 + 2] + ad2 + eam * sh2));
    float es3 = __expf(lrelu(a_src[(size_t)n * 4 + 3] + ad3 + eam * sh3));

    uint2 xv = embq[(size_t)n * 64 + lane];     // self loop row
    float d0 = bflo(xv.x), d1 = bfhi(xv.x), d2 = bflo(xv.y), d3 = bfhi(xv.y);

    float a00 = es0 * d0, a01 = es0 * d1, a02 = es0 * d2, a03 = es0 * d3;
    float a10 = es1 * d0, a11 = es1 * d1, a12 = es1 * d2, a13 = es1 * d3;
    float a20 = es2 * d0, a21 = es2 * d1, a22 = es2 * d2, a23 = es2 * d3;
    float a30 = es3 * d0, a31 = es3 * d1, a32 = es3 * d2, a33 = es3 * d3;
    float den0 = es0, den1 = es1, den2 = es2, den3 = es3;

    for (int cb = beg; cb < end; cb += 64) {
        int m = end - cb; if (m > 64) m = 64;
        if (lane < m) {
            int e = csr[cb + lane];
            int s = edge_read(ei, is64, (size_t)e);
            float wgt = ew[e];
            s_src[wid][lane] = s;
            float4 as4 = *reinterpret_cast<const float4*>(&a_src[(size_t)s * 4]);
            s_alpha[wid][lane][0] = __expf(lrelu(as4.x + ad0 + wgt * sh0));
            s_alpha[wid][lane][1] = __expf(lrelu(as4.y + ad1 + wgt * sh1));
            s_alpha[wid][lane][2] = __expf(lrelu(as4.z + ad2 + wgt * sh2));
            s_alpha[wid][lane][3] = __expf(lrelu(as4.w + ad3 + wgt * sh3));
        }
        // per-wave LDS slice + same-wave ordering: no barrier needed
        int e2 = 0;
        for (; e2 + 2 <= m; e2 += 2) {
            int s0 = s_src[wid][e2], s1 = s_src[wid][e2 + 1];
            float4 w0 = *reinterpret_cast<const float4*>(s_alpha[wid][e2]);
            float4 w1 = *reinterpret_cast<const float4*>(s_alpha[wid][e2 + 1]);
            uint2 v0 = embq[(size_t)s0 * 64 + lane];
            uint2 v1 = embq[(size_t)s1 * 64 + lane];
            EFMA(w0, v0); EFMA(w1, v1);
        }
        if (e2 < m) {
            int s0 = s_src[wid][e2];
            float4 w0 = *reinterpret_cast<const float4*>(s_alpha[wid][e2]);
            uint2 v0 = embq[(size_t)s0 * 64 + lane];
            EFMA(w0, v0);
        }
    }

    float i0 = 1.f / (den0 + 1e-16f), i1 = 1.f / (den1 + 1e-16f);
    float i2 = 1.f / (den2 + 1e-16f), i3 = 1.f / (den3 + 1e-16f);
    size_t base = (size_t)n * 256 + lane;       // uint2 units; head stride 64
    uint2 o;
    o.x = (unsigned)f2bf(a00 * i0) | ((unsigned)f2bf(a01 * i0) << 16);
    o.y = (unsigned)f2bf(a02 * i0) | ((unsigned)f2bf(a03 * i0) << 16);
    aggn[base] = o;
    o.x = (unsigned)f2bf(a10 * i1) | ((unsigned)f2bf(a11 * i1) << 16);
    o.y = (unsigned)f2bf(a12 * i1) | ((unsigned)f2bf(a13 * i1) << 16);
    aggn[base + 64] = o;
    o.x = (unsigned)f2bf(a20 * i2) | ((unsigned)f2bf(a21 * i2) << 16);
    o.y = (unsigned)f2bf(a22 * i2) | ((unsigned)f2bf(a23 * i2) << 16);
    aggn[base + 128] = o;
    o.x = (unsigned)f2bf(a30 * i3) | ((unsigned)f2bf(a31 * i3) << 16);
    o.y = (unsigned)f2bf(a32 * i3) | ((unsigned)f2bf(a33 * i3) << 16);
    aggn[base + 192] = o;
}

// ---------------------------------------------------------------------------
// Output GEMM: out[M][256] = aggn[M][1024] @ MT[256][1024]^T + sum(bc4).
// 128x256 tile (A read exactly once), 512 threads, 8 waves, BK=64.
__global__ __launch_bounds__(512) void gemm_out_kernel(
        const unsigned short* __restrict__ A,
        const unsigned short* __restrict__ BT,
        const float* __restrict__ bc4, float* __restrict__ C, int M) {
    __shared__ __align__(16) unsigned short As[128 * 64];   // 16 KB
    __shared__ __align__(16) unsigned short Bs[256 * 64];   // 32 KB
    int tid = threadIdx.x;
    int lane = tid & 63, w = tid >> 6;
    int bm = blockIdx.x * 128;
    int wr = w >> 2, wc = w & 3;

    f32x4 acc[4][4];
    #pragma unroll
    for (int i = 0; i < 4; ++i)
        #pragma unroll
        for (int j = 0; j < 4; ++j)
            acc[i][j] = (f32x4){0.f, 0.f, 0.f, 0.f};

    int lr = lane & 15, kb = lane >> 4;
    int q = lane & 7;

    for (int k0 = 0; k0 < 1024; k0 += 64) {
        #pragma unroll
        for (int p = 0; p < 2; ++p) {
            int row = p * 64 + w * 8 + (lane >> 3);
            int ce  = ((q ^ (row & 7)) << 3) + k0;
            int ob  = p * 8192 + w * 1024;
            int gr = bm + row; if (gr >= M) gr = M - 1;
            GLOAD16(A + (size_t)gr * 1024 + ce, (char*)As + ob);
        }
        #pragma unroll
        for (int p = 0; p < 4; ++p) {
            int row = p * 64 + w * 8 + (lane >> 3);
            int ce  = ((q ^ (row & 7)) << 3) + k0;
            int ob  = p * 8192 + w * 1024;
            GLOAD16(BT + (size_t)row * 1024 + ce, (char*)Bs + ob);
        }
        __syncthreads();

        #pragma unroll
        for (int kk = 0; kk < 2; ++kk) {
            bf16x8 a[4], b[4];
            #pragma unroll
            for (int i = 0; i < 4; ++i) {
                int row = wr * 64 + i * 16 + lr;
                a[i] = *reinterpret_cast<const bf16x8*>(
                    &As[row * 64 + (((kk * 4 + kb) ^ (row & 7)) << 3)]);
            }
            #pragma unroll
            for (int j = 0; j < 4; ++j) {
                int row = wc * 64 + j * 16 + lr;
                b[j] = *reinterpret_cast<const bf16x8*>(
                    &Bs[row * 64 + (((kk * 4 + kb) ^ (row & 7)) << 3)]);
            }
            #pragma unroll
            for (int i = 0; i < 4; ++i)
                #pragma unroll
                for (int j = 0; j < 4; ++j)
                    acc[i][j] = __builtin_amdgcn_mfma_f32_16x16x32_bf16(a[i], b[j], acc[i][j], 0, 0, 0);
        }
        __syncthreads();
    }

    int rg = lane >> 4;
    #pragma unroll
    for (int i = 0; i < 4; ++i) {
        #pragma unroll
        for (int r = 0; r < 4; ++r) {
            int row = bm + wr * 64 + i * 16 + rg * 4 + r;
            if (row >= M) continue;
            #pragma unroll
            for (int j = 0; j < 4; ++j) {
                int col = wc * 64 + j * 16 + lr;
                float bval = bc4[col] + bc4[256 + col] + bc4[512 + col] + bc4[768 + col];
                C[(size_t)row * 256 + col] = acc[i][j][r] + bval;
            }
        }
    }
}

// ---------------------------------------------------------------------------
extern "C" void kernel_launch(void* const* d_in, const int* in_sizes, int n_in,
                              void* d_out, int out_size, void* d_ws, size_t ws_size,
                              hipStream_t stream) {
    const int*   edge_index  = (const int*)d_in[0];
    const float* edge_weight = (const float*)d_in[1];
    const float* emb         = (const float*)d_in[2];
    const float* W           = (const float*)d_in[3];
    const float* att_src     = (const float*)d_in[4];
    const float* att_dst     = (const float*)d_in[5];
    const float* att_edge    = (const float*)d_in[6];
    const float* W_edge      = (const float*)d_in[7];
    const float* bias        = (const float*)d_in[8];
    const float* W_out       = (const float*)d_in[9];
    const float* b_out       = (const float*)d_in[10];
    float* out = (float*)d_out;

    const int E = in_sizes[1];
    const int D = 256;
    const int N = in_sizes[2] / D;
    const int nb = (N + 255) / 256;            // scan blocks (196 <= 256 CUs)
    const int mb = (N + 127) / 128;
    const int nEmb = (N + 15) / 16;
    const int nEdge = (E + 255) / 256;

    char* ws = (char*)d_ws;
    size_t off = 0;
    auto alloc = [&](size_t bytes) {
        size_t o = off;
        off += (bytes + 255) & ~(size_t)255;
        return o;
    };
    unsigned short* embb  = (unsigned short*)(ws + alloc((size_t)N * D * 2));       // [N][256]
    unsigned short* aggn  = (unsigned short*)(ws + alloc((size_t)N * 1024 * 2));    // [N][4*256]
    unsigned short* Wb    = (unsigned short*)(ws + alloc((size_t)D * HC * 2));      // [256][512]
    unsigned short* WoT   = (unsigned short*)(ws + alloc((size_t)HC * D * 2));      // [256][512]
    unsigned short* MT    = (unsigned short*)(ws + alloc((size_t)256 * 1024 * 2));  // [256][1024]
    float* watt    = (float*)(ws + alloc(2048 * 4));
    float* bc4     = (float*)(ws + alloc(1024 * 4));
    float* a_src   = (float*)(ws + alloc((size_t)N * 4 * 4));
    float* a_dst   = (float*)(ws + alloc((size_t)N * 4 * 4));
    float* sh      = (float*)(ws + alloc(64));
    float* ea_mean = (float*)(ws + alloc((size_t)N * 4));
    size_t zbytes  = (size_t)N * 12 + 1024;                // wsum | cnt | fill | gsum
    size_t zoff    = alloc(zbytes + 16);
    float* wsum    = (float*)(ws + zoff);
    int*   cnt     = (int*)(ws + zoff + (size_t)N * 4);
    int*   fillc   = (int*)(ws + zoff + (size_t)N * 8);
    int*   gsum    = (int*)(ws + zoff + (size_t)N * 12);
    int*   offsets = (int*)(ws + alloc((size_t)(N + 1) * 4));
    int*   csr     = (int*)(ws + alloc((size_t)E * 4));
    int*   flag    = (int*)(ws + alloc(4));
    (void)ws_size; (void)n_in; (void)out_size;

    int zcount = (int)((zbytes + 15) / 16);                // uint4 units
    int nzb = (zcount + 255) / 256;

    // 1) weight prep + probe + zeroing
    wprep_kernel<<<654 + nzb, 256, 0, stream>>>(
        W, W_out, att_src, att_dst, W_edge, att_edge, bias, b_out,
        edge_index, E, Wb, WoT, watt, bc4, sh, flag, (uint4*)(ws + zoff), zcount);

    // 2) MT gemm + emb cast/attdot + edge stats
    mega1_kernel<<<16 + nEmb + nEdge, 256, 0, stream>>>(
        WoT, Wb, MT, (const float4*)emb, watt, (uint2*)embb, a_src, a_dst,
        N, nEmb, edge_index, edge_weight, flag, cnt, wsum, E);

    // 3) single-dispatch lookback scan (+ ea_mean)
    scan_kernel<<<nb, 256, 0, stream>>>(cnt, wsum, offsets, ea_mean, gsum, N, E);

    // 4) CSR fill
    fill_kernel<<<nEdge, 256, 0, stream>>>(edge_index, flag, offsets, fillc, csr, E);

    // 5) aggregation in emb space
    agg_kernel<<<(N + 3) / 4, 256, 0, stream>>>(
        (const uint2*)embb, a_src, a_dst, ea_mean, sh, edge_weight, edge_index,
        flag, csr, offsets, (uint2*)aggn, N);

    // 6) out = aggn @ MT^T + bc
    gemm_out_kernel<<<mb, 512, 0, stream>>>(aggn, MT, bc4, out, N);
}